// Round 12
// baseline (373.030 us; speedup 1.0000x reference)
//
#include <hip/hip_runtime.h>
#include <hip/hip_bf16.h>

#define L_TXT 256
#define L_IMG 1024
#define L_TMP 1024
#define LTOT  2304
#define DMODEL 1024
#define NH 16
#define HDIM 64
#define DMLP 4096
#define EPSV 1e-6f

typedef unsigned short ushort;
typedef __attribute__((ext_vector_type(8))) short short8b;   // 8 x bf16
typedef __attribute__((ext_vector_type(8))) unsigned short ushort8v;
typedef __attribute__((ext_vector_type(4))) float f32x4;
typedef __attribute__((ext_vector_type(4))) unsigned short ushort4v;

// ---- workspace layout (bytes) ----
#define MOD_OFF    ((size_t)0)                       // f32 3*6144
#define XM_OFF     ((size_t)73728)                   // bf16 2304*1024
#define QKV_OFF    ((size_t)4792320)                 // bf16 2304*3072 (t1 overlays)
#define QB_OFF     ((size_t)18948096)                // bf16 16*2304*64 ; f32 mlp2 partial0 overlays post-attn
#define KB_OFF     ((size_t)23666688)
#define VTB_OFF    ((size_t)28385280)                // f32 mlp2 partial1 overlays post-attn
#define ATT_OFF    ((size_t)33103872)                // bf16 2304*1024 (mod partials overlay pre-attn)
#define S1_OFF     ((size_t)37822464)                // f32 2304*1024
#define QKVWT_OFF  ((size_t)49356800)                // bf16 3*3072*1024
#define PROJWT_OFF ((size_t)68231168)                // bf16 3*1024*1024
#define W1T_OFF    ((size_t)74522624)                // bf16 3*4096*1024
#define W2T_OFF    ((size_t)99688448)                // bf16 3*1024*4096 (if ws large)
#define W2T_END    ((size_t)124854272)

static __device__ __forceinline__ ushort f2bf(float x) {
    __hip_bfloat16 b = __float2bfloat16(x);
    return *reinterpret_cast<ushort*>(&b);
}
static __device__ __forceinline__ float bf2f(ushort u) {
    return __uint_as_float(((unsigned)u) << 16);
}

typedef __attribute__((address_space(1))) const unsigned char gas_t;
typedef __attribute__((address_space(3))) unsigned char las_t;
static __device__ __forceinline__ void gload16(const void* g, void* l) {
    __builtin_amdgcn_global_load_lds((gas_t*)g, (las_t*)l, 16, 0, 0);
}

// ---- conv tile body with non-temporal option (f32 [K][N] -> bf16 [N][K], 64k x 128n) ----
template<bool NT>
static __device__ __forceinline__ void conv_tile(const float* __restrict__ W,
                                                 ushort* __restrict__ WT,
                                                 int K, int N, int nt, int kt,
                                                 float (*tb)[132], int tid) {
    {
        int r = tid >> 5, c4 = (tid & 31) * 4;
#pragma unroll
        for (int i = 0; i < 8; i++) {
            const f32x4* src = reinterpret_cast<const f32x4*>(W + (size_t)(kt*64 + r + i*8) * N + nt*128 + c4);
            f32x4 v = NT ? __builtin_nontemporal_load(src) : *src;
            tb[r + i*8][c4+0] = v.x; tb[r + i*8][c4+1] = v.y;
            tb[r + i*8][c4+2] = v.z; tb[r + i*8][c4+3] = v.w;
        }
    }
    __syncthreads();
    {
        int n = tid >> 1, k32 = (tid & 1) * 32;
        ushort* dst = WT + (size_t)(nt*128 + n) * K + kt*64 + k32;
#pragma unroll
        for (int j2 = 0; j2 < 4; j2++) {
            ushort8v u;
#pragma unroll
            for (int i = 0; i < 8; i++) u[i] = f2bf(tb[k32 + j2*8 + i][n]);
            if (NT) __builtin_nontemporal_store(u, reinterpret_cast<ushort8v*>(dst + j2*8));
            else    *reinterpret_cast<ushort8v*>(dst + j2*8) = u;
        }
    }
}

// ---------------- phase-1: mod GEMV partials (576) + qkv weight tiles (1152) ----------------
__global__ __launch_bounds__(256) void k_conv_a(const float* __restrict__ vec,
                                                const float* __restrict__ modw,
                                                float* __restrict__ modp,
                                                const float* __restrict__ qkvw,
                                                ushort* __restrict__ qkvwt) {
    __shared__ float tb[64][132];
    int bid = blockIdx.x;
    int tid = threadIdx.x;
    if (bid < 576) {
        float* svs = &tb[0][0];
        float* pl  = &tb[0][0] + 256;
        int g0 = (bid >> 2) * 128;
        int ks = bid & 3;
        int i  = g0 / 6144;
        int j0 = g0 - i * 6144;
        {
            float v = vec[ks*256 + tid];
            svs[tid] = v / (1.0f + __expf(-v));
        }
        __syncthreads();
        int jl = tid & 31, ko = tid >> 5;
        const float* wp = modw + (size_t)i * 1024 * 6144 + (size_t)(ks*256) * 6144 + j0 + jl*4;
        float a0x=0.f,a0y=0.f,a0z=0.f,a0w=0.f;
        float a1x=0.f,a1y=0.f,a1z=0.f,a1w=0.f;
#pragma unroll 4
        for (int kk = 0; kk < 16; kk++) {
            int k0 = kk*16 + ko;
            int k1 = k0 + 8;
            float4 w0 = *reinterpret_cast<const float4*>(wp + (size_t)k0 * 6144);
            float4 w1v = *reinterpret_cast<const float4*>(wp + (size_t)k1 * 6144);
            float s0 = svs[k0], s1 = svs[k1];
            a0x += s0*w0.x; a0y += s0*w0.y; a0z += s0*w0.z; a0w += s0*w0.w;
            a1x += s1*w1v.x; a1y += s1*w1v.y; a1z += s1*w1v.z; a1w += s1*w1v.w;
        }
        pl[ko*128 + jl*4+0] = a0x + a1x;
        pl[ko*128 + jl*4+1] = a0y + a1y;
        pl[ko*128 + jl*4+2] = a0z + a1z;
        pl[ko*128 + jl*4+3] = a0w + a1w;
        __syncthreads();
        if (tid < 128) {
            float s = 0.f;
#pragma unroll
            for (int k = 0; k < 8; k++) s += pl[k*128 + tid];
            modp[(size_t)ks*18432 + g0 + tid] = s;
        }
        return;
    }
    int b = bid - 576;                  // qkv: 16 x 24 tiles per s
    int s = b / 384, r = b % 384;
    conv_tile<false>(qkvw + (size_t)s * 1024 * 3072, qkvwt + (size_t)s * 3072 * 1024,
                     1024, 3072, r % 24, r / 24, tb, tid);
}

// mod partial reduce
__global__ __launch_bounds__(256) void k_modr(const float* __restrict__ p,
                                              const float* __restrict__ modb,
                                              float* __restrict__ mod) {
    int g = blockIdx.x * 256 + threadIdx.x;
    float s = p[g] + p[18432 + g] + p[2*18432 + g] + p[3*18432 + g];
    mod[g] = s + modb[g];
}

// standalone slice transpose (w2 fallback): grid (N/128, K/64)
__global__ __launch_bounds__(256) void k_conv_slice(const float* __restrict__ W,
                                                    ushort* __restrict__ WT,
                                                    int K, int N) {
    __shared__ float tb[64][132];
    conv_tile<false>(W, WT, K, N, blockIdx.x, blockIdx.y, tb, threadIdx.x);
}

// ---------------- fused: QKV MFMA GEMM (432 blocks) + proj/w1/w2 conversion tail (nt) ----------------
__global__ __launch_bounds__(256) void k_qkv_conv(const ushort* __restrict__ xm,
                                                  const ushort* __restrict__ qkvwt,
                                                  ushort* __restrict__ qkv,
                                                  const float* __restrict__ projw,
                                                  const float* __restrict__ w1,
                                                  const float* __restrict__ w2,
                                                  ushort* __restrict__ projwt,
                                                  ushort* __restrict__ w1t,
                                                  ushort* __restrict__ w2t) {
    __shared__ union {
        struct { ushort A[128*64]; ushort B[128*64]; } g;
        float tb[64][132];
    } sm;
    const int tid = threadIdx.x;

    if (blockIdx.x >= 432) {
        int b = blockIdx.x - 432;
        if (b < 384) {                  // proj: 8 x 16 per s
            int s = b / 128, r = b % 128;
            conv_tile<true>(projw + (size_t)s * 1024 * 1024, projwt + (size_t)s * 1024 * 1024,
                            1024, 1024, r % 8, r / 8, sm.tb, tid);
        } else if (b < 1920) {          // w1: 32 x 16 per s
            b -= 384; int s = b / 512, r = b % 512;
            conv_tile<true>(w1 + (size_t)s * 1024 * 4096, w1t + (size_t)s * 4096 * 1024,
                            1024, 4096, r % 32, r / 32, sm.tb, tid);
        } else {                        // w2: 8 x 64 per s (bigws only)
            b -= 1920; int s = b / 512, r = b % 512;
            conv_tile<true>(w2 + (size_t)s * 4096 * 1024, w2t + (size_t)s * 1024 * 4096,
                            4096, 1024, r % 8, r / 8, sm.tb, tid);
        }
        return;
    }

    // ---- QKV GEMM: BM=BN=128, K=1024, N=3072, multi-stream rows ----
    const int nx = blockIdx.x % 24, ny = blockIdx.x / 24;
    const int brow = ny * 128;
    int s;
    if (brow < 256)       { s = 2; }
    else if (brow < 1280) { s = 0; }
    else                  { s = 1; }
    const int arow = brow;   // xm/qkv are contiguous in global row order

    const ushort* A = xm + (size_t)arow * DMODEL;
    const ushort* BTs = qkvwt + (size_t)s * 3072 * 1024;
    ushort* Cl = qkv + (size_t)arow * 3072;

    const int lane = tid & 63, w = tid >> 6;
    const int wr = w >> 1, wc = w & 1;
    const int bn = nx * 128;
    const int r15 = lane & 15, g4 = lane >> 4;

    f32x4 acc[4][4];
#pragma unroll
    for (int i = 0; i < 4; i++)
#pragma unroll
        for (int j = 0; j < 4; j++) acc[i][j] = (f32x4){0.f,0.f,0.f,0.f};

    for (int k0 = 0; k0 < 1024; k0 += 64) {
#pragma unroll
        for (int i = 0; i < 4; i++) {
            int chunk = i*4 + w;
            int seg = chunk*64 + lane;
            int row = seg >> 3;
            int gs  = (seg & 7) ^ (row & 7);
            gload16(A + (size_t)row * 1024 + k0 + gs*8, sm.g.A + (size_t)chunk * 512);
        }
#pragma unroll
        for (int i = 0; i < 4; i++) {
            int chunk = i*4 + w;
            int seg = chunk*64 + lane;
            int row = seg >> 3;
            int gs  = (seg & 7) ^ (row & 7);
            gload16(BTs + (size_t)(bn + row) * 1024 + k0 + gs*8, sm.g.B + (size_t)chunk * 512);
        }
        __syncthreads();
#pragma unroll
        for (int kk = 0; kk < 2; kk++) {
            short8b a[4], b[4];
#pragma unroll
            for (int mi = 0; mi < 4; mi++) {
                int row = wr*64 + mi*16 + r15;
                int c   = kk*4 + g4;
                a[mi] = *reinterpret_cast<const short8b*>(&sm.g.A[row*64 + ((c ^ (row & 7)))*8]);
            }
#pragma unroll
            for (int ni = 0; ni < 4; ni++) {
                int row = wc*64 + ni*16 + r15;
                int c   = kk*4 + g4;
                b[ni] = *reinterpret_cast<const short8b*>(&sm.g.B[row*64 + ((c ^ (row & 7)))*8]);
            }
#pragma unroll
            for (int mi = 0; mi < 4; mi++)
#pragma unroll
                for (int ni = 0; ni < 4; ni++)
                    acc[mi][ni] = __builtin_amdgcn_mfma_f32_16x16x32_bf16(a[mi], b[ni], acc[mi][ni], 0, 0, 0);
        }
        __syncthreads();
    }

#pragma unroll
    for (int mi = 0; mi < 4; mi++) {
#pragma unroll
        for (int ni = 0; ni < 4; ni++) {
            int col = bn + wc*64 + ni*16 + r15;
#pragma unroll
            for (int r = 0; r < 4; r++) {
                int rr = wr*64 + mi*16 + g4*4 + r;
                Cl[(size_t)rr * 3072 + col] = f2bf(acc[mi][ni][r]);
            }
        }
    }
}

// ---------------- LN + (1+sc)*x + sh -> bf16, stream-select (inputs) ----------------
__global__ __launch_bounds__(256) void k_ln_mod1(const float* __restrict__ img,
                                                 const float* __restrict__ tmp,
                                                 const float* __restrict__ txt,
                                                 const float* __restrict__ mod,
                                                 ushort* __restrict__ xm) {
    int l = blockIdx.x;
    const float* src; int strm;
    if (l < L_TXT)              { src = txt + (size_t)l * DMODEL;            strm = 2; }
    else if (l < L_TXT + L_IMG) { src = img + (size_t)(l - L_TXT) * DMODEL;  strm = 0; }
    else                        { src = tmp + (size_t)(l - L_TXT - L_IMG) * DMODEL; strm = 1; }

    int d = threadIdx.x * 4;
    float4 x = *reinterpret_cast<const float4*>(src + d);
    float s  = x.x + x.y + x.z + x.w;
    float s2 = x.x*x.x + x.y*x.y + x.z*x.z + x.w*x.w;
#pragma unroll
    for (int o = 32; o > 0; o >>= 1) { s += __shfl_xor(s, o); s2 += __shfl_xor(s2, o); }
    __shared__ float red[8];
    int wave = threadIdx.x >> 6, lane = threadIdx.x & 63;
    if (lane == 0) { red[wave*2] = s; red[wave*2+1] = s2; }
    __syncthreads();
    if (threadIdx.x == 0) {
        float a = 0.f, b = 0.f;
        for (int w = 0; w < 4; w++) { a += red[w*2]; b += red[w*2+1]; }
        red[0] = a; red[1] = b;
    }
    __syncthreads();
    float mean = red[0] * (1.0f/DMODEL);
    float var  = red[1] * (1.0f/DMODEL) - mean*mean;
    float inv  = rsqrtf(var + EPSV);

    const float* sh = mod + strm*6144;
    const float* sc = sh + 1024;
    float4 shv = *reinterpret_cast<const float4*>(sh + d);
    float4 scv = *reinterpret_cast<const float4*>(sc + d);
    ushort4v o;
    o.x = f2bf((1.f+scv.x)*((x.x-mean)*inv) + shv.x);
    o.y = f2bf((1.f+scv.y)*((x.y-mean)*inv) + shv.y);
    o.z = f2bf((1.f+scv.z)*((x.z-mean)*inv) + shv.z);
    o.w = f2bf((1.f+scv.w)*((x.w-mean)*inv) + shv.w);
    *reinterpret_cast<ushort4v*>(xm + (size_t)l*DMODEL + d) = o;
}

// ---------------- generic LN + modulate -> bf16 (explicit pointers) ----------------
__global__ __launch_bounds__(256) void k_ln_mod2(const float* __restrict__ src,
                                                 const float* __restrict__ sh,
                                                 const float* __restrict__ sc,
                                                 ushort* __restrict__ out) {
    int r = blockIdx.x;
    const float* srow = src + (size_t)r * DMODEL;
    int d = threadIdx.x * 4;
    float4 x = *reinterpret_cast<const float4*>(srow + d);
    float s  = x.x + x.y + x.z + x.w;
    float s2 = x.x*x.x + x.y*x.y + x.z*x.z + x.w*x.w;
#pragma unroll
    for (int o = 32; o > 0; o >>= 1) { s += __shfl_xor(s, o); s2 += __shfl_xor(s2, o); }
    __shared__ float red[8];
    int wave = threadIdx.x >> 6, lane = threadIdx.x & 63;
    if (lane == 0) { red[wave*2] = s; red[wave*2+1] = s2; }
    __syncthreads();
    if (threadIdx.x == 0) {
        float a = 0.f, b = 0.f;
        for (int w = 0; w < 4; w++) { a += red[w*2]; b += red[w*2+1]; }
        red[0] = a; red[1] = b;
    }
    __syncthreads();
    float mean = red[0] * (1.0f/DMODEL);
    float var  = red[1] * (1.0f/DMODEL) - mean*mean;
    float inv  = rsqrtf(var + EPSV);
    float4 shv = *reinterpret_cast<const float4*>(sh + d);
    float4 scv = *reinterpret_cast<const float4*>(sc + d);
    ushort4v o;
    o.x = f2bf((1.f+scv.x)*((x.x-mean)*inv) + shv.x);
    o.y = f2bf((1.f+scv.y)*((x.y-mean)*inv) + shv.y);
    o.z = f2bf((1.f+scv.z)*((x.z-mean)*inv) + shv.z);
    o.w = f2bf((1.f+scv.w)*((x.w-mean)*inv) + shv.w);
    *reinterpret_cast<ushort4v*>(out + (size_t)r*DMODEL + d) = o;
}

// ---------------- phase-A LN: global rows 0..1279 of s1 (txt then img) ----------------
__global__ __launch_bounds__(256) void k_ln_modg(const float* __restrict__ s1,
                                                 const float* __restrict__ mod,
                                                 ushort* __restrict__ xm) {
    int row = blockIdx.x;
    int strm = row < 256 ? 2 : 0;
    const float* srow = s1 + (size_t)row * DMODEL;
    int d = threadIdx.x * 4;
    float4 x = *reinterpret_cast<const float4*>(srow + d);
    float s  = x.x + x.y + x.z + x.w;
    float s2 = x.x*x.x + x.y*x.y + x.z*x.z + x.w*x.w;
#pragma unroll
    for (int o = 32; o > 0; o >>= 1) { s += __shfl_xor(s, o); s2 += __shfl_xor(s2, o); }
    __shared__ float red[8];
    int wave = threadIdx.x >> 6, lane = threadIdx.x & 63;
    if (lane == 0) { red[wave*2] = s; red[wave*2+1] = s2; }
    __syncthreads();
    if (threadIdx.x == 0) {
        float a = 0.f, b = 0.f;
        for (int w = 0; w < 4; w++) { a += red[w*2]; b += red[w*2+1]; }
        red[0] = a; red[1] = b;
    }
    __syncthreads();
    float mean = red[0] * (1.0f/DMODEL);
    float var  = red[1] * (1.0f/DMODEL) - mean*mean;
    float inv  = rsqrtf(var + EPSV);
    const float* sh = mod + strm*6144 + 3*1024;
    const float* sc = mod + strm*6144 + 4*1024;
    float4 shv = *reinterpret_cast<const float4*>(sh + d);
    float4 scv = *reinterpret_cast<const float4*>(sc + d);
    ushort4v o;
    o.x = f2bf((1.f+scv.x)*((x.x-mean)*inv) + shv.x);
    o.y = f2bf((1.f+scv.y)*((x.y-mean)*inv) + shv.y);
    o.z = f2bf((1.f+scv.z)*((x.z-mean)*inv) + shv.z);
    o.w = f2bf((1.f+scv.w)*((x.w-mean)*inv) + shv.w);
    *reinterpret_cast<ushort4v*>(xm + (size_t)row*DMODEL + d) = o;
}

// ---------------- multi-stream bf16 MFMA GEMM, templated BM/BN, BK=64 ----------------
__device__ __forceinline__ float gelu_fast(float x) {
    return x / (1.0f + __expf(-1.5957691216057308f * (x + 0.044715f * x * x * x)));
}

template<int MODE, int BM, int BN, typename OutT>
__global__ __launch_bounds__(256) void k_gemm_ms(const ushort* __restrict__ A_t,
                                                 const ushort* __restrict__ A_i,
                                                 const ushort* __restrict__ A_m,
                                                 const ushort* __restrict__ BT,
                                                 const float* __restrict__ bias,
                                                 const float* __restrict__ res_t,
                                                 const float* __restrict__ res_i,
                                                 const float* __restrict__ res_m,
                                                 const float* __restrict__ mod, int gidx,
                                                 OutT* __restrict__ out_t,
                                                 OutT* __restrict__ out_i,
                                                 OutT* __restrict__ out_m,
                                                 int N, int K, int ry0) {
    constexpr int MI = BM / 32;
    constexpr int NI = BN / 32;
    const int brow = (ry0 + blockIdx.y) * BM;
    int s, lrow;
    if (brow < 256)       { s = 2; lrow = brow; }
    else if (brow < 1280) { s = 0; lrow = brow - 256; }
    else                  { s = 1; lrow = brow - 1280; }

    const ushort* A = (s==2 ? A_t : s==0 ? A_i : A_m) + (size_t)lrow * K;
    const ushort* BTs = BT + (size_t)s * N * K;
    const float* bi = (MODE != 3 && bias) ? bias + (size_t)s * N : nullptr;
    const float* resl = (MODE==2) ? ((s==2 ? res_t : s==0 ? res_i : res_m) + (size_t)lrow * N) : nullptr;
    const float* gate = (MODE==2) ? (mod + s*6144 + gidx*1024) : nullptr;
    OutT* Cl;
    if (MODE == 3) Cl = (blockIdx.z == 0 ? out_t : out_i) + (size_t)brow * N;
    else           Cl = (s==2 ? out_t : s==0 ? out_i : out_m) + (size_t)lrow * N;

    const int kbeg = (MODE == 3) ? blockIdx.z * (K >> 1) : 0;
    const int kend = (MODE == 3) ? kbeg + (K >> 1) : K;

    __shared__ ushort Asl[BM*64];
    __shared__ ushort Bsl[BN*64];
    const int tid = threadIdx.x;
    const int lane = tid & 63, w = tid >> 6;
    const int wr = w >> 1, wc = w & 1;
    const int bn = blockIdx.x * BN;
    const int r15 = lane & 15, g4 = lane >> 4;

    f32x4 acc[MI][NI];
#pragma unroll
    for (int i = 0; i < MI; i++)
#pragma unroll
        for (int j = 0; j < NI; j++) acc[i][j] = (f32x4){0.f,0.f,0.f,0.f};

    for (int k0 = kbeg; k0 < kend; k0 += 64) {
#pragma unroll
        for (int i = 0; i < BM/32; i++) {
            int chunk = i*4 + w;
            int seg = chunk*64 + lane;
            int row = seg >> 3;
            int gs  = (seg & 7) ^ (row & 7);
            gload16(A + (size_t)row * K + k0 + gs*8, Asl + (size_t)chunk * 512);
        }
#pragma unroll
        for (int i = 0; i < BN/32; i++) {
            int chunk = i*4 + w;
            int seg = chunk*64 + lane;
            int row = seg >> 3;
            int gs  = (seg & 7) ^ (row & 7);
            gload16(BTs + (size_t)(bn + row) * K + k0 + gs*8, Bsl + (size_t)chunk * 512);
        }
        __syncthreads();
#pragma unroll
        for (int kk = 0; kk < 2; kk++) {
            short8b a[MI], b[NI];
#pragma unroll
            for (int mi = 0; mi < MI; mi++) {
                int row = wr*(MI*16) + mi*16 + r15;
                int c   = kk*4 + g4;
                a[mi] = *reinterpret_cast<const short8b*>(&Asl[row*64 + ((c ^ (row & 7)))*8]);
            }
#pragma unroll
            for (int ni = 0; ni < NI; ni++) {
                int row = wc*(NI*16) + ni*16 + r15;
                int c   = kk*4 + g4;
                b[ni] = *reinterpret_cast<const short8b*>(&Bsl[row*64 + ((c ^ (row & 7)))*8]);
            }
#pragma unroll
            for (int mi = 0; mi < MI; mi++)
#pragma unroll
                for (int ni = 0; ni < NI; ni++)
                    acc[mi][ni] = __builtin_amdgcn_mfma_f32_16x16x32_bf16(a[mi], b[ni], acc[mi][ni], 0, 0, 0);
        }
        __syncthreads();
    }

#pragma unroll
    for (int mi = 0; mi < MI; mi++) {
#pragma unroll
        for (int ni = 0; ni < NI; ni++) {
            int col = bn + wc*(NI*16) + ni*16 + r15;
            float bv = bi ? bi[col] : 0.f;
#pragma unroll
            for (int r = 0; r < 4; r++) {
                int rr = wr*(MI*16) + mi*16 + g4*4 + r;
                float v = acc[mi][ni][r] + bv;
                if (MODE == 1) v = gelu_fast(v);
                if (MODE == 2) v = resl[(size_t)rr * N + col] + gate[col] * v;
                if (sizeof(OutT) == 2) Cl[(size_t)rr * N + col] = (OutT)f2bf(v);
                else                   Cl[(size_t)rr * N + col] = (OutT)v;
            }
        }
    }
}

// ---------------- mlp2 split-K combine: out = res + gate*(p0+p1+b2) ----------------
__global__ __launch_bounds__(256) void k_mlp2fin(const float* __restrict__ p0,
                                                 const float* __restrict__ p1,
                                                 const float* __restrict__ b2,
                                                 const float* __restrict__ s1,
                                                 const float* __restrict__ mod,
                                                 float* __restrict__ out_t,
                                                 float* __restrict__ out_i,
                                                 float* __restrict__ out_m,
                                                 int row0) {
    int row = row0 + blockIdx.x;
    int s, lrow;
    if (row < 256)       { s = 2; lrow = row; }
    else if (row < 1280) { s = 0; lrow = row - 256; }
    else                 { s = 1; lrow = row - 1280; }
    const float* gate = mod + s*6144 + 5*1024;
    const float* bias = b2 + s*1024;
    float* outp = (s==2 ? out_t : s==0 ? out_i : out_m) + (size_t)lrow * DMODEL;
    int d = threadIdx.x * 4;
    float4 a = *reinterpret_cast<const float4*>(p0 + (size_t)row*DMODEL + d);
    float4 b = *reinterpret_cast<const float4*>(p1 + (size_t)row*DMODEL + d);
    float4 r = *reinterpret_cast<const float4*>(s1 + (size_t)row*DMODEL + d);
    float4 g = *reinterpret_cast<const float4*>(gate + d);
    float4 bi = *reinterpret_cast<const float4*>(bias + d);
    float4 o;
    o.x = r.x + g.x*(a.x + b.x + bi.x);
    o.y = r.y + g.y*(a.y + b.y + bi.y);
    o.z = r.z + g.z*(a.z + b.z + bi.z);
    o.w = r.w + g.w*(a.w + b.w + bi.w);
    *reinterpret_cast<float4*>(outp + d) = o;
}

// ---------------- qkv finalize + V transpose: block = (h, 64-l tile) ----------------
__global__ __launch_bounds__(256) void k_qkvfin(const ushort* __restrict__ qkv,
                                                const float* __restrict__ pe,
                                                const float* __restrict__ qs,
                                                const float* __restrict__ ks,
                                                ushort* __restrict__ Q,
                                                ushort* __restrict__ K,
                                                ushort* __restrict__ VT) {
    const int tid = threadIdx.x;
    const int w = tid >> 6, lane = tid & 63;
    const int h  = blockIdx.x / 36;
    const int l0 = (blockIdx.x % 36) * 64;
    __shared__ ushort vbuf[64][65];

    for (int it = 0; it < 16; it++) {
        int ll = it*4 + w;
        int l = l0 + ll;
        int strm;
        if (l < L_TXT) strm = 2; else if (l < L_TXT + L_IMG) strm = 0; else strm = 1;
        const ushort* row = qkv + (size_t)l * 3 * DMODEL + h*HDIM + lane;
        float q = bf2f(row[0]);
        float k = bf2f(row[DMODEL]);
        float v = bf2f(row[2*DMODEL]);

        float sq = q*q, sk = k*k;
#pragma unroll
        for (int o = 32; o > 0; o >>= 1) { sq += __shfl_xor(sq, o); sk += __shfl_xor(sk, o); }
        float rq = q * rsqrtf(sq * (1.0f/HDIM) + EPSV) * qs[strm*HDIM + lane];
        float rk = k * rsqrtf(sk * (1.0f/HDIM) + EPSV) * ks[strm*HDIM + lane];

        // BUG replication: temporal stream's V is its RMS'd Q (pre-RoPE)
        float vout = (strm == 1) ? rq : v;

        float rq_p = __shfl_xor(rq, 1);
        float rk_p = __shfl_xor(rk, 1);
        float qe = (lane & 1) ? rq_p : rq;
        float qo = (lane & 1) ? rq : rq_p;
        float ke = (lane & 1) ? rk_p : rk;
        float ko = (lane & 1) ? rk : rk_p;
        const float* pel = pe + (size_t)l*128 + (lane >> 1)*4 + (lane & 1)*2;
        float qr = pel[0]*qe + pel[1]*qo;
        float kr = pel[0]*ke + pel[1]*ko;

        size_t idx = ((size_t)h * LTOT + l) * HDIM + lane;
        Q[idx] = f2bf(qr);
        K[idx] = f2bf(kr);
        vbuf[ll][lane] = f2bf(vout);
    }
    __syncthreads();
    {
        int d = tid >> 2, ls = (tid & 3) * 16;
        ushort8v u0, u1;
#pragma unroll
        for (int i = 0; i < 8; i++) u0[i] = vbuf[ls+i][d];
#pragma unroll
        for (int i = 0; i < 8; i++) u1[i] = vbuf[ls+8+i][d];
        ushort* dst = VT + ((size_t)h * 64 + d) * LTOT + l0 + ls;
        *reinterpret_cast<ushort8v*>(dst)     = u0;
        *reinterpret_cast<ushort8v*>(dst + 8) = u1;
    }
}

// ---------------- MFMA flash attention: LDS K/V dbuf + prefetch + setprio + skip-rescale ----------------
__global__ __launch_bounds__(256) void k_attn_mfma(const ushort* __restrict__ Qb,
                                                   const ushort* __restrict__ Kb,
                                                   const ushort* __restrict__ VTb,
                                                   ushort* __restrict__ att) {
    const int tid = threadIdx.x;
    const int w = tid >> 6, lane = tid & 63;
    const int h  = blockIdx.x / 36;
    const int qt = blockIdx.x % 36;
    const int qbase = qt*64 + w*16;
    const int g = lane >> 4;
    const int q = lane & 15;

    __shared__ ushort Ksl[2][64*64];
    __shared__ ushort Vsl[2][64*64];
    __shared__ ushort plds[4][1024];
    ushort* P = plds[w];

    const ushort* Kg = Kb  + (size_t)h * LTOT * 64;
    const ushort* Vg = VTb + (size_t)h * 64 * LTOT;

    const ushort* qp = Qb + ((size_t)h * LTOT + qbase + q) * 64 + g*8;
    const short8b qf0 = *reinterpret_cast<const short8b*>(qp);
    const short8b qf1 = *reinterpret_cast<const short8b*>(qp + 32);

    f32x4 out[4];
#pragma unroll
    for (int d = 0; d < 4; d++) out[d] = (f32x4){0.f,0.f,0.f,0.f};
    float m = -1e30f, lsum = 0.f;

#pragma unroll
    for (int i = 0; i < 2; i++) {
        int seg = i*256 + tid;
        int row = seg >> 3;
        int gs  = (seg & 7) ^ (row & 7);
        gload16(Kg + (size_t)row*64 + gs*8, &Ksl[0][(size_t)(i*256 + w*64)*8]);
        gload16(Vg + (size_t)row*LTOT + gs*8, &Vsl[0][(size_t)(i*256 + w*64)*8]);
    }

    for (int t = 0; t < 36; t++) {
        const int cb = t & 1;
        __syncthreads();
        if (t < 35) {
            int kvn = (t+1) * 64;
#pragma unroll
            for (int i = 0; i < 2; i++) {
                int seg = i*256 + tid;
                int row = seg >> 3;
                int gs  = (seg & 7) ^ (row & 7);
                gload16(Kg + (size_t)(kvn + row)*64 + gs*8, &Ksl[cb^1][(size_t)(i*256 + w*64)*8]);
                gload16(Vg + (size_t)row*LTOT + kvn + gs*8, &Vsl[cb^1][(size_t)(i*256 + w*64)*8]);
            }
        }

        f32x4 s[4];
        __builtin_amdgcn_s_setprio(1);
#pragma unroll
        for (int ks = 0; ks < 4; ks++) {
            int r = ks*16 + q;
            short8b kf0 = *reinterpret_cast<const short8b*>(&Ksl[cb][r*64 + ((g     ^ (r & 7)))*8]);
            short8b kf1 = *reinterpret_cast<const short8b*>(&Ksl[cb][r*64 + (((4+g) ^ (r & 7)))*8]);
            f32x4 acc = (f32x4){0.f,0.f,0.f,0.f};
            acc = __builtin_amdgcn_mfma_f32_16x16x32_bf16(kf0, qf0, acc, 0, 0, 0);
            acc = __builtin_amdgcn_mfma_f32_16x16x32_bf16(kf1, qf1, acc, 0, 0, 0);
            s[ks] = acc;
        }
        __builtin_amdgcn_s_setprio(0);

        float m0 = fmaxf(fmaxf(s[0][0], s[0][1]), s[0][2]);
        float m1 = fmaxf(fmaxf(s[0][3], s[1][0]), s[1][1]);
        float m2 = fmaxf(fmaxf(s[1][2], s[1][3]), s[2][0]);
        float m3 = fmaxf(fmaxf(s[2][1], s[2][2]), s[2][3]);
        float m4 = fmaxf(fmaxf(s[3][0], s[3][1]), s[3][2]);
        float t5 = fmaxf(fmaxf(m0, m1), m2);
        float t6 = fmaxf(fmaxf(m3, m4), s[3][3]);
        float tmax = fmaxf(t5, t6);
        tmax = fmaxf(tmax, __shfl_xor(tmax, 16));
        tmax = fmaxf(tmax, __shfl_xor(tmax, 32));
        float pm = tmax * 0.125f;
        if (!__all(pm <= m)) {
            float newm = fmaxf(m, pm);
            float c = __expf(m - newm);
            lsum *= c;
#pragma unroll
            for (int d = 0; d < 4; d++) out[d] *= c;
            m = newm;
        }
        float p[16];
        float tsum = 0.f;
#pragma unroll
        for (int ks = 0; ks < 4; ks++)
#pragma unroll
            for (int r = 0; r < 4; r++) {
                float pv = __expf(s[ks][r] * 0.125f - m);
                p[ks*4+r] = pv;
                tsum += pv;
            }
        tsum += __shfl_xor(tsum, 16);
        tsum += __shfl_xor(tsum, 32);
        lsum += tsum;

#pragma unroll
        for (int ks = 0; ks < 4; ks++) {
            ushort4v pk;
            pk.x = f2bf(p[ks*4+0]); pk.y = f2bf(p[ks*4+1]);
            pk.z = f2bf(p[ks*4+2]); pk.w = f2bf(p[ks*4+3]);
            int widx = (q*64 + ks*16 + g*4) ^ ((q & 7) << 3);
            *reinterpret_cast<ushort4v*>(&P[widx]) = pk;
        }
        __builtin_amdgcn_s_setprio(1);
#pragma unroll
        for (int c2 = 0; c2 < 2; c2++) {
            int ridx = (q*64 + c2*32 + g*8) ^ ((q & 7) << 3);
            short8b pf = *reinterpret_cast<const short8b*>(&P[ridx]);
#pragma unroll
            for (int ds = 0; ds < 4; ds++) {
                int d = ds*16 + q;
                short8b vf = *reinterpret_cast<const short8b*>(&Vsl[cb][d*64 + (((c2*4+g) ^ (d & 7)))*8]);
                out[ds] = __builtin_amdgcn_mfma_f32_16x16x32_bf16(vf, pf, out[ds], 0, 0, 0);
            }
        }
        __builtin_amdgcn_s_setprio(0);
    }

    float inv = 1.0f / lsum;
    ushort* orow = att + (size_t)(qbase + q) * DMODEL + h * HDIM;
#pragma unroll
    for (int ds = 0; ds < 4; ds++) {
        ushort4v o4;
        o4.x = f2bf(out[ds][0]*inv); o4.y = f2bf(out[ds][1]*inv);
        o4.z = f2bf(out[ds][2]*inv); o4.w = f2bf(out[ds][3]*inv);
        *reinterpret_cast<ushort4v*>(orow + ds*16 + g*4) = o4;
    }
}

// ---------------- launch ----------------
extern "C" void kernel_launch(void* const* d_in, const int* in_sizes, int n_in,
                              void* d_out, int out_size, void* d_ws, size_t ws_size,
                              hipStream_t stream) {
    const float* img  = (const float*)d_in[0];
    const float* tmp  = (const float*)d_in[1];
    const float* txt  = (const float*)d_in[2];
    const float* vec  = (const float*)d_in[3];
    const float* pe   = (const float*)d_in[4];
    const float* modw = (const float*)d_in[5];
    const float* modb = (const float*)d_in[6];
    const float* qkvw = (const float*)d_in[7];
    const float* qsc  = (const float*)d_in[8];
    const float* ksc  = (const float*)d_in[9];
    const float* projw= (const float*)d_in[10];
    const float* projb= (const float*)d_in[11];
    const float* w1   = (const float*)d_in[12];
    const float* b1   = (const float*)d_in[13];
    const float* w2   = (const float*)d_in[14];
    const float* b2   = (const float*)d_in[15];

    char* wsb = (char*)d_ws;
    float*  mod    = (float*) (wsb + MOD_OFF);
    ushort* xm     = (ushort*)(wsb + XM_OFF);
    ushort* qkv    = (ushort*)(wsb + QKV_OFF);
    ushort* t1     = (ushort*)(wsb + QKV_OFF);
    ushort* Qb     = (ushort*)(wsb + QB_OFF);
    ushort* Kb     = (ushort*)(wsb + KB_OFF);
    ushort* VTb    = (ushort*)(wsb + VTB_OFF);
    float*  p0buf  = (float*) (wsb + QB_OFF);
    float*  p1buf  = (float*) (wsb + VTB_OFF);
    float*  modp   = (float*) (wsb + ATT_OFF);
    ushort* att    = (ushort*)(wsb + ATT_OFF);
    float*  s1     = (float*) (wsb + S1_OFF);
    ushort* qkvwt  = (ushort*)(wsb + QKVWT_OFF);
    ushort* projwt = (ushort*)(wsb + PROJWT_OFF);
    ushort* w1t    = (ushort*)(wsb + W1T_OFF);

    const bool bigws = ws_size >= W2T_END;
    ushort* w2t = bigws ? (ushort*)(wsb + W2T_OFF) : w1t;

    float* out_img = (float*)d_out;
    float* out_tmp = out_img + (size_t)L_IMG * DMODEL;
    float* out_txt = out_tmp + (size_t)L_TMP * DMODEL;

    // phase-1: mod GEMV partials + qkv weight conversion
    k_conv_a<<<576 + 1152, 256, 0, stream>>>(vec, modw, modp, qkvw, qkvwt);
    k_modr<<<72, 256, 0, stream>>>(modp, modb, mod);
    k_ln_mod1<<<LTOT, 256, 0, stream>>>(img, tmp, txt, mod, xm);

    // fused: QKV GEMM (432) + proj/w1(/w2) conversion tail (non-temporal)
    int qc_blocks = 432 + (bigws ? 3456 : 1920);
    k_qkv_conv<<<qc_blocks, 256, 0, stream>>>(xm, qkvwt, qkv,
                                              projw, w1, w2, projwt, w1t, w2t);

    k_qkvfin<<<NH*36, 256, 0, stream>>>(qkv, pe, qsc, ksc, Qb, Kb, VTb);
    k_attn_mfma<<<NH*36, 256, 0, stream>>>(Qb, Kb, VTb, att);

    // proj + residual + gate1 -> s1 (BM=64: 288 blocks)
    k_gemm_ms<2, 64, 128, float><<<dim3(8, 36), 256, 0, stream>>>(
        att, att + (size_t)256*DMODEL, att + (size_t)1280*DMODEL,
        projwt, projb, txt, img, tmp, mod, 2,
        s1, s1 + (size_t)256*DMODEL, s1 + (size_t)1280*DMODEL, DMODEL, DMODEL, 0);

    // ---- phase A: txt + img MLP ----
    k_ln_modg<<<1280, 256, 0, stream>>>(s1, mod, xm);
    k_gemm_ms<1, 64, 128, ushort><<<dim3(32, 20), 256, 0, stream>>>(
        xm, xm + (size_t)256*DMODEL, xm + (size_t)1280*DMODEL,
        w1t, b1, nullptr, nullptr, nullptr, nullptr, 0,
        t1, t1 + (size_t)256*DMLP, t1, DMLP, DMODEL, 0);
    if (!bigws) {
        k_conv_slice<<<dim3(8, 64), 256, 0, stream>>>(w2,                          w1t,                          DMLP, DMODEL);
        k_conv_slice<<<dim3(8, 64), 256, 0, stream>>>(w2 + (size_t)2*DMLP*DMODEL,  w1t + (size_t)2*DMLP*DMODEL,  DMLP, DMODEL);
    }
    // mlp2 phase A: split-K=2 partials + combine
    k_gemm_ms<3, 64, 128, float><<<dim3(8, 20, 2), 256, 0, stream>>>(
        t1, t1 + (size_t)256*DMLP, t1,
        w2t, nullptr, nullptr, nullptr, nullptr, nullptr, 0,
        p0buf, p1buf, nullptr, DMODEL, DMLP, 0);
    k_mlp2fin<<<1280, 256, 0, stream>>>(p0buf, p1buf, b2, s1, mod,
                                        out_txt, out_img, out_tmp, 0);

    // ---- phase B: temporal MLP (LN input is FINAL img — reference quirk) ----
    k_ln_mod2<<<L_TMP, 256, 0, stream>>>(out_img, mod + 1*6144 + 3*1024, mod + 1*6144 + 4*1024, xm + (size_t)1280*DMODEL);
    k_gemm_ms<1, 64, 128, ushort><<<dim3(32, 16), 256, 0, stream>>>(
        xm, xm + (size_t)256*DMODEL, xm + (size_t)1280*DMODEL,
        w1t, b1, nullptr, nullptr, nullptr, nullptr, 0,
        t1, t1, t1, DMLP, DMODEL, 20);
    if (!bigws) {
        k_conv_slice<<<dim3(8, 64), 256, 0, stream>>>(w2 + (size_t)DMLP*DMODEL, w1t + (size_t)DMLP*DMODEL, DMLP, DMODEL);
    }
    // mlp2 phase B: split-K=2 partials + combine
    k_gemm_ms<3, 64, 128, float><<<dim3(8, 16, 2), 256, 0, stream>>>(
        t1, t1, t1,
        w2t, nullptr, nullptr, nullptr, nullptr, nullptr, 0,
        p0buf, p1buf, nullptr, DMODEL, DMLP, 20);
    k_mlp2fin<<<1024, 256, 0, stream>>>(p0buf, p1buf, b2, s1, mod,
                                        out_txt, out_img, out_tmp, 1280);
}

// Round 13
// 302.828 us; speedup vs baseline: 1.2318x; 1.2318x over previous
//
#include <hip/hip_runtime.h>
#include <hip/hip_bf16.h>

#define L_TXT 256
#define L_IMG 1024
#define L_TMP 1024
#define LTOT  2304
#define DMODEL 1024
#define NH 16
#define HDIM 64
#define DMLP 4096
#define EPSV 1e-6f

typedef unsigned short ushort;
typedef __attribute__((ext_vector_type(8))) short short8b;   // 8 x bf16
typedef __attribute__((ext_vector_type(8))) unsigned short ushort8v;
typedef __attribute__((ext_vector_type(4))) float f32x4;
typedef __attribute__((ext_vector_type(4))) unsigned short ushort4v;

// ---- workspace layout (bytes) ----
#define MOD_OFF    ((size_t)0)                       // f32 3*6144
#define XM_OFF     ((size_t)73728)                   // bf16 2304*1024
#define QKV_OFF    ((size_t)4792320)                 // bf16 2304*3072 (t1 overlays)
#define QB_OFF     ((size_t)18948096)                // bf16 16*2304*64 ; f32 mlp2 partial0 overlays post-attn
#define KB_OFF     ((size_t)23666688)
#define VTB_OFF    ((size_t)28385280)                // f32 mlp2 partial1 overlays post-attn
#define ATT_OFF    ((size_t)33103872)                // bf16 2304*1024 (mod partials overlay pre-attn)
#define S1_OFF     ((size_t)37822464)                // f32 2304*1024
#define QKVWT_OFF  ((size_t)49356800)                // bf16 3*3072*1024
#define PROJWT_OFF ((size_t)68231168)                // bf16 3*1024*1024
#define W1T_OFF    ((size_t)74522624)                // bf16 3*4096*1024
#define W2T_OFF    ((size_t)99688448)                // bf16 3*1024*4096 (if ws large)
#define W2T_END    ((size_t)124854272)

static __device__ __forceinline__ ushort f2bf(float x) {
    __hip_bfloat16 b = __float2bfloat16(x);
    return *reinterpret_cast<ushort*>(&b);
}
static __device__ __forceinline__ float bf2f(ushort u) {
    return __uint_as_float(((unsigned)u) << 16);
}

typedef __attribute__((address_space(1))) const unsigned char gas_t;
typedef __attribute__((address_space(3))) unsigned char las_t;
static __device__ __forceinline__ void gload16(const void* g, void* l) {
    __builtin_amdgcn_global_load_lds((gas_t*)g, (las_t*)l, 16, 0, 0);
}

// ---- conv tile body (f32 [K][N] -> bf16 [N][K], 64k x 128n) ----
static __device__ __forceinline__ void conv_tile(const float* __restrict__ W,
                                                 ushort* __restrict__ WT,
                                                 int K, int N, int nt, int kt,
                                                 float (*tb)[132], int tid) {
    {
        int r = tid >> 5, c4 = (tid & 31) * 4;
#pragma unroll
        for (int i = 0; i < 8; i++) {
            float4 v = *reinterpret_cast<const float4*>(W + (size_t)(kt*64 + r + i*8) * N + nt*128 + c4);
            tb[r + i*8][c4+0] = v.x; tb[r + i*8][c4+1] = v.y;
            tb[r + i*8][c4+2] = v.z; tb[r + i*8][c4+3] = v.w;
        }
    }
    __syncthreads();
    {
        int n = tid >> 1, k32 = (tid & 1) * 32;
        ushort* dst = WT + (size_t)(nt*128 + n) * K + kt*64 + k32;
#pragma unroll
        for (int j2 = 0; j2 < 4; j2++) {
            ushort8v u;
#pragma unroll
            for (int i = 0; i < 8; i++) u[i] = f2bf(tb[k32 + j2*8 + i][n]);
            *reinterpret_cast<ushort8v*>(dst + j2*8) = u;
        }
    }
}

// ---------------- fused: mod GEMV partials (576) + all weight transpose tiles ----------------
__global__ __launch_bounds__(256) void k_conv(const float* __restrict__ vec,
                                              const float* __restrict__ modw,
                                              float* __restrict__ modp,
                                              const float* __restrict__ qkvw,
                                              const float* __restrict__ projw,
                                              const float* __restrict__ w1,
                                              const float* __restrict__ w2,
                                              ushort* __restrict__ qkvwt,
                                              ushort* __restrict__ projwt,
                                              ushort* __restrict__ w1t,
                                              ushort* __restrict__ w2t) {
    __shared__ float tb[64][132];
    int bid = blockIdx.x;
    int tid = threadIdx.x;
    if (bid < 576) {
        // ---- mod GEMV partial: K-slice of 256, dual accumulator chains ----
        float* svs = &tb[0][0];             // 256 floats
        float* pl  = &tb[0][0] + 256;       // 8 x 128
        int g0 = (bid >> 2) * 128;
        int ks = bid & 3;
        int i  = g0 / 6144;
        int j0 = g0 - i * 6144;
        {
            float v = vec[ks*256 + tid];
            svs[tid] = v / (1.0f + __expf(-v));
        }
        __syncthreads();
        int jl = tid & 31, ko = tid >> 5;
        const float* wp = modw + (size_t)i * 1024 * 6144 + (size_t)(ks*256) * 6144 + j0 + jl*4;
        float a0x=0.f,a0y=0.f,a0z=0.f,a0w=0.f;
        float a1x=0.f,a1y=0.f,a1z=0.f,a1w=0.f;
#pragma unroll 4
        for (int kk = 0; kk < 16; kk++) {
            int k0 = kk*16 + ko;
            int k1 = k0 + 8;
            float4 w0 = *reinterpret_cast<const float4*>(wp + (size_t)k0 * 6144);
            float4 w1v = *reinterpret_cast<const float4*>(wp + (size_t)k1 * 6144);
            float s0 = svs[k0], s1 = svs[k1];
            a0x += s0*w0.x; a0y += s0*w0.y; a0z += s0*w0.z; a0w += s0*w0.w;
            a1x += s1*w1v.x; a1y += s1*w1v.y; a1z += s1*w1v.z; a1w += s1*w1v.w;
        }
        pl[ko*128 + jl*4+0] = a0x + a1x;
        pl[ko*128 + jl*4+1] = a0y + a1y;
        pl[ko*128 + jl*4+2] = a0z + a1z;
        pl[ko*128 + jl*4+3] = a0w + a1w;
        __syncthreads();
        if (tid < 128) {
            float s = 0.f;
#pragma unroll
            for (int k = 0; k < 8; k++) s += pl[k*128 + tid];
            modp[(size_t)ks*18432 + g0 + tid] = s;
        }
        return;
    }
    int b = bid - 576;
    if (b < 1152) {                 // qkv: K=1024, N=3072 -> 16 x 24 tiles per s
        int s = b / 384, r = b % 384;
        conv_tile(qkvw + (size_t)s * 1024 * 3072, qkvwt + (size_t)s * 3072 * 1024,
                  1024, 3072, r % 24, r / 24, tb, tid);
    } else if (b < 1536) {          // proj: 16 x 8
        b -= 1152; int s = b / 128, r = b % 128;
        conv_tile(projw + (size_t)s * 1024 * 1024, projwt + (size_t)s * 1024 * 1024,
                  1024, 1024, r % 8, r / 8, tb, tid);
    } else if (b < 3072) {          // w1: 16 x 32
        b -= 1536; int s = b / 512, r = b % 512;
        conv_tile(w1 + (size_t)s * 1024 * 4096, w1t + (size_t)s * 4096 * 1024,
                  1024, 4096, r % 32, r / 32, tb, tid);
    } else {                        // w2: K=4096, N=1024 -> 64 x 8 (bigws only)
        b -= 3072; int s = b / 512, r = b % 512;
        conv_tile(w2 + (size_t)s * 4096 * 1024, w2t + (size_t)s * 1024 * 4096,
                  4096, 1024, r % 8, r / 8, tb, tid);
    }
}

// mod partial reduce
__global__ __launch_bounds__(256) void k_modr(const float* __restrict__ p,
                                              const float* __restrict__ modb,
                                              float* __restrict__ mod) {
    int g = blockIdx.x * 256 + threadIdx.x;
    float s = p[g] + p[18432 + g] + p[2*18432 + g] + p[3*18432 + g];
    mod[g] = s + modb[g];
}

// standalone slice transpose (w2 fallback): grid (N/128, K/64)
__global__ __launch_bounds__(256) void k_conv_slice(const float* __restrict__ W,
                                                    ushort* __restrict__ WT,
                                                    int K, int N) {
    __shared__ float tb[64][132];
    conv_tile(W, WT, K, N, blockIdx.x, blockIdx.y, tb, threadIdx.x);
}

// ---------------- LN + (1+sc)*x + sh -> bf16, stream-select (inputs) ----------------
__global__ __launch_bounds__(256) void k_ln_mod1(const float* __restrict__ img,
                                                 const float* __restrict__ tmp,
                                                 const float* __restrict__ txt,
                                                 const float* __restrict__ mod,
                                                 ushort* __restrict__ xm) {
    int l = blockIdx.x;
    const float* src; int strm;
    if (l < L_TXT)              { src = txt + (size_t)l * DMODEL;            strm = 2; }
    else if (l < L_TXT + L_IMG) { src = img + (size_t)(l - L_TXT) * DMODEL;  strm = 0; }
    else                        { src = tmp + (size_t)(l - L_TXT - L_IMG) * DMODEL; strm = 1; }

    int d = threadIdx.x * 4;
    float4 x = *reinterpret_cast<const float4*>(src + d);
    float s  = x.x + x.y + x.z + x.w;
    float s2 = x.x*x.x + x.y*x.y + x.z*x.z + x.w*x.w;
#pragma unroll
    for (int o = 32; o > 0; o >>= 1) { s += __shfl_xor(s, o); s2 += __shfl_xor(s2, o); }
    __shared__ float red[8];
    int wave = threadIdx.x >> 6, lane = threadIdx.x & 63;
    if (lane == 0) { red[wave*2] = s; red[wave*2+1] = s2; }
    __syncthreads();
    if (threadIdx.x == 0) {
        float a = 0.f, b = 0.f;
        for (int w = 0; w < 4; w++) { a += red[w*2]; b += red[w*2+1]; }
        red[0] = a; red[1] = b;
    }
    __syncthreads();
    float mean = red[0] * (1.0f/DMODEL);
    float var  = red[1] * (1.0f/DMODEL) - mean*mean;
    float inv  = rsqrtf(var + EPSV);

    const float* sh = mod + strm*6144;
    const float* sc = sh + 1024;
    float4 shv = *reinterpret_cast<const float4*>(sh + d);
    float4 scv = *reinterpret_cast<const float4*>(sc + d);
    ushort4v o;
    o.x = f2bf((1.f+scv.x)*((x.x-mean)*inv) + shv.x);
    o.y = f2bf((1.f+scv.y)*((x.y-mean)*inv) + shv.y);
    o.z = f2bf((1.f+scv.z)*((x.z-mean)*inv) + shv.z);
    o.w = f2bf((1.f+scv.w)*((x.w-mean)*inv) + shv.w);
    *reinterpret_cast<ushort4v*>(xm + (size_t)l*DMODEL + d) = o;
}

// ---------------- generic LN + modulate -> bf16 (explicit pointers) ----------------
__global__ __launch_bounds__(256) void k_ln_mod2(const float* __restrict__ src,
                                                 const float* __restrict__ sh,
                                                 const float* __restrict__ sc,
                                                 ushort* __restrict__ out) {
    int r = blockIdx.x;
    const float* srow = src + (size_t)r * DMODEL;
    int d = threadIdx.x * 4;
    float4 x = *reinterpret_cast<const float4*>(srow + d);
    float s  = x.x + x.y + x.z + x.w;
    float s2 = x.x*x.x + x.y*x.y + x.z*x.z + x.w*x.w;
#pragma unroll
    for (int o = 32; o > 0; o >>= 1) { s += __shfl_xor(s, o); s2 += __shfl_xor(s2, o); }
    __shared__ float red[8];
    int wave = threadIdx.x >> 6, lane = threadIdx.x & 63;
    if (lane == 0) { red[wave*2] = s; red[wave*2+1] = s2; }
    __syncthreads();
    if (threadIdx.x == 0) {
        float a = 0.f, b = 0.f;
        for (int w = 0; w < 4; w++) { a += red[w*2]; b += red[w*2+1]; }
        red[0] = a; red[1] = b;
    }
    __syncthreads();
    float mean = red[0] * (1.0f/DMODEL);
    float var  = red[1] * (1.0f/DMODEL) - mean*mean;
    float inv  = rsqrtf(var + EPSV);
    float4 shv = *reinterpret_cast<const float4*>(sh + d);
    float4 scv = *reinterpret_cast<const float4*>(sc + d);
    ushort4v o;
    o.x = f2bf((1.f+scv.x)*((x.x-mean)*inv) + shv.x);
    o.y = f2bf((1.f+scv.y)*((x.y-mean)*inv) + shv.y);
    o.z = f2bf((1.f+scv.z)*((x.z-mean)*inv) + shv.z);
    o.w = f2bf((1.f+scv.w)*((x.w-mean)*inv) + shv.w);
    *reinterpret_cast<ushort4v*>(out + (size_t)r*DMODEL + d) = o;
}

// ---------------- phase-A LN: global rows 0..1279 of s1 (txt then img) ----------------
__global__ __launch_bounds__(256) void k_ln_modg(const float* __restrict__ s1,
                                                 const float* __restrict__ mod,
                                                 ushort* __restrict__ xm) {
    int row = blockIdx.x;
    int strm = row < 256 ? 2 : 0;
    const float* srow = s1 + (size_t)row * DMODEL;
    int d = threadIdx.x * 4;
    float4 x = *reinterpret_cast<const float4*>(srow + d);
    float s  = x.x + x.y + x.z + x.w;
    float s2 = x.x*x.x + x.y*x.y + x.z*x.z + x.w*x.w;
#pragma unroll
    for (int o = 32; o > 0; o >>= 1) { s += __shfl_xor(s, o); s2 += __shfl_xor(s2, o); }
    __shared__ float red[8];
    int wave = threadIdx.x >> 6, lane = threadIdx.x & 63;
    if (lane == 0) { red[wave*2] = s; red[wave*2+1] = s2; }
    __syncthreads();
    if (threadIdx.x == 0) {
        float a = 0.f, b = 0.f;
        for (int w = 0; w < 4; w++) { a += red[w*2]; b += red[w*2+1]; }
        red[0] = a; red[1] = b;
    }
    __syncthreads();
    float mean = red[0] * (1.0f/DMODEL);
    float var  = red[1] * (1.0f/DMODEL) - mean*mean;
    float inv  = rsqrtf(var + EPSV);
    const float* sh = mod + strm*6144 + 3*1024;
    const float* sc = mod + strm*6144 + 4*1024;
    float4 shv = *reinterpret_cast<const float4*>(sh + d);
    float4 scv = *reinterpret_cast<const float4*>(sc + d);
    ushort4v o;
    o.x = f2bf((1.f+scv.x)*((x.x-mean)*inv) + shv.x);
    o.y = f2bf((1.f+scv.y)*((x.y-mean)*inv) + shv.y);
    o.z = f2bf((1.f+scv.z)*((x.z-mean)*inv) + shv.z);
    o.w = f2bf((1.f+scv.w)*((x.w-mean)*inv) + shv.w);
    *reinterpret_cast<ushort4v*>(xm + (size_t)row*DMODEL + d) = o;
}

// ---------------- multi-stream bf16 MFMA GEMM, templated BM/BN, BK=64 ----------------
// MODE 0: C=A@W(+b) bf16   MODE 1: gelu   MODE 2: res+gate*(...)   MODE 3: split-K f32 partial (blockIdx.z)
__device__ __forceinline__ float gelu_fast(float x) {
    return x / (1.0f + __expf(-1.5957691216057308f * (x + 0.044715f * x * x * x)));
}

template<int MODE, int BM, int BN, typename OutT>
__global__ __launch_bounds__(256) void k_gemm_ms(const ushort* __restrict__ A_t,
                                                 const ushort* __restrict__ A_i,
                                                 const ushort* __restrict__ A_m,
                                                 const ushort* __restrict__ BT,
                                                 const float* __restrict__ bias,
                                                 const float* __restrict__ res_t,
                                                 const float* __restrict__ res_i,
                                                 const float* __restrict__ res_m,
                                                 const float* __restrict__ mod, int gidx,
                                                 OutT* __restrict__ out_t,
                                                 OutT* __restrict__ out_i,
                                                 OutT* __restrict__ out_m,
                                                 int N, int K, int ry0) {
    constexpr int MI = BM / 32;
    constexpr int NI = BN / 32;
    const int brow = (ry0 + blockIdx.y) * BM;
    int s, lrow;
    if (brow < 256)       { s = 2; lrow = brow; }
    else if (brow < 1280) { s = 0; lrow = brow - 256; }
    else                  { s = 1; lrow = brow - 1280; }

    const ushort* A = (s==2 ? A_t : s==0 ? A_i : A_m) + (size_t)lrow * K;
    const ushort* BTs = BT + (size_t)s * N * K;
    const float* bi = (MODE != 3 && bias) ? bias + (size_t)s * N : nullptr;
    const float* resl = (MODE==2) ? ((s==2 ? res_t : s==0 ? res_i : res_m) + (size_t)lrow * N) : nullptr;
    const float* gate = (MODE==2) ? (mod + s*6144 + gidx*1024) : nullptr;
    OutT* Cl;
    if (MODE == 3) Cl = (blockIdx.z == 0 ? out_t : out_i) + (size_t)brow * N;
    else           Cl = (s==2 ? out_t : s==0 ? out_i : out_m) + (size_t)lrow * N;

    const int kbeg = (MODE == 3) ? blockIdx.z * (K >> 1) : 0;
    const int kend = (MODE == 3) ? kbeg + (K >> 1) : K;

    __shared__ ushort Asl[BM*64];
    __shared__ ushort Bsl[BN*64];
    const int tid = threadIdx.x;
    const int lane = tid & 63, w = tid >> 6;
    const int wr = w >> 1, wc = w & 1;
    const int bn = blockIdx.x * BN;
    const int r15 = lane & 15, g4 = lane >> 4;

    f32x4 acc[MI][NI];
#pragma unroll
    for (int i = 0; i < MI; i++)
#pragma unroll
        for (int j = 0; j < NI; j++) acc[i][j] = (f32x4){0.f,0.f,0.f,0.f};

    for (int k0 = kbeg; k0 < kend; k0 += 64) {
#pragma unroll
        for (int i = 0; i < BM/32; i++) {
            int chunk = i*4 + w;
            int seg = chunk*64 + lane;
            int row = seg >> 3;
            int gs  = (seg & 7) ^ (row & 7);
            gload16(A + (size_t)row * K + k0 + gs*8, Asl + (size_t)chunk * 512);
        }
#pragma unroll
        for (int i = 0; i < BN/32; i++) {
            int chunk = i*4 + w;
            int seg = chunk*64 + lane;
            int row = seg >> 3;
            int gs  = (seg & 7) ^ (row & 7);
            gload16(BTs + (size_t)(bn + row) * K + k0 + gs*8, Bsl + (size_t)chunk * 512);
        }
        __syncthreads();
#pragma unroll
        for (int kk = 0; kk < 2; kk++) {
            short8b a[MI], b[NI];
#pragma unroll
            for (int mi = 0; mi < MI; mi++) {
                int row = wr*(MI*16) + mi*16 + r15;
                int c   = kk*4 + g4;
                a[mi] = *reinterpret_cast<const short8b*>(&Asl[row*64 + ((c ^ (row & 7)))*8]);
            }
#pragma unroll
            for (int ni = 0; ni < NI; ni++) {
                int row = wc*(NI*16) + ni*16 + r15;
                int c   = kk*4 + g4;
                b[ni] = *reinterpret_cast<const short8b*>(&Bsl[row*64 + ((c ^ (row & 7)))*8]);
            }
#pragma unroll
            for (int mi = 0; mi < MI; mi++)
#pragma unroll
                for (int ni = 0; ni < NI; ni++)
                    acc[mi][ni] = __builtin_amdgcn_mfma_f32_16x16x32_bf16(a[mi], b[ni], acc[mi][ni], 0, 0, 0);
        }
        __syncthreads();
    }

#pragma unroll
    for (int mi = 0; mi < MI; mi++) {
#pragma unroll
        for (int ni = 0; ni < NI; ni++) {
            int col = bn + wc*(NI*16) + ni*16 + r15;
            float bv = bi ? bi[col] : 0.f;
#pragma unroll
            for (int r = 0; r < 4; r++) {
                int rr = wr*(MI*16) + mi*16 + g4*4 + r;
                float v = acc[mi][ni][r] + bv;
                if (MODE == 1) v = gelu_fast(v);
                if (MODE == 2) v = resl[(size_t)rr * N + col] + gate[col] * v;
                if (sizeof(OutT) == 2) Cl[(size_t)rr * N + col] = (OutT)f2bf(v);
                else                   Cl[(size_t)rr * N + col] = (OutT)v;
            }
        }
    }
}

// ---------------- mlp2 split-K combine: out = res + gate*(p0+p1+b2) ----------------
__global__ __launch_bounds__(256) void k_mlp2fin(const float* __restrict__ p0,
                                                 const float* __restrict__ p1,
                                                 const float* __restrict__ b2,
                                                 const float* __restrict__ s1,
                                                 const float* __restrict__ mod,
                                                 float* __restrict__ out_t,
                                                 float* __restrict__ out_i,
                                                 float* __restrict__ out_m,
                                                 int row0) {
    int row = row0 + blockIdx.x;
    int s, lrow;
    if (row < 256)       { s = 2; lrow = row; }
    else if (row < 1280) { s = 0; lrow = row - 256; }
    else                 { s = 1; lrow = row - 1280; }
    const float* gate = mod + s*6144 + 5*1024;
    const float* bias = b2 + s*1024;
    float* outp = (s==2 ? out_t : s==0 ? out_i : out_m) + (size_t)lrow * DMODEL;
    int d = threadIdx.x * 4;
    float4 a = *reinterpret_cast<const float4*>(p0 + (size_t)row*DMODEL + d);
    float4 b = *reinterpret_cast<const float4*>(p1 + (size_t)row*DMODEL + d);
    float4 r = *reinterpret_cast<const float4*>(s1 + (size_t)row*DMODEL + d);
    float4 g = *reinterpret_cast<const float4*>(gate + d);
    float4 bi = *reinterpret_cast<const float4*>(bias + d);
    float4 o;
    o.x = r.x + g.x*(a.x + b.x + bi.x);
    o.y = r.y + g.y*(a.y + b.y + bi.y);
    o.z = r.z + g.z*(a.z + b.z + bi.z);
    o.w = r.w + g.w*(a.w + b.w + bi.w);
    *reinterpret_cast<float4*>(outp + d) = o;
}

// ---------------- qkv finalize + V transpose: block = (h, 64-l tile) ----------------
__global__ __launch_bounds__(256) void k_qkvfin(const ushort* __restrict__ qkv,
                                                const float* __restrict__ pe,
                                                const float* __restrict__ qs,
                                                const float* __restrict__ ks,
                                                ushort* __restrict__ Q,
                                                ushort* __restrict__ K,
                                                ushort* __restrict__ VT) {
    const int tid = threadIdx.x;
    const int w = tid >> 6, lane = tid & 63;
    const int h  = blockIdx.x / 36;
    const int l0 = (blockIdx.x % 36) * 64;
    __shared__ ushort vbuf[64][65];

    for (int it = 0; it < 16; it++) {
        int ll = it*4 + w;
        int l = l0 + ll;
        int strm;
        if (l < L_TXT) strm = 2; else if (l < L_TXT + L_IMG) strm = 0; else strm = 1;
        const ushort* row = qkv + (size_t)l * 3 * DMODEL + h*HDIM + lane;
        float q = bf2f(row[0]);
        float k = bf2f(row[DMODEL]);
        float v = bf2f(row[2*DMODEL]);

        float sq = q*q, sk = k*k;
#pragma unroll
        for (int o = 32; o > 0; o >>= 1) { sq += __shfl_xor(sq, o); sk += __shfl_xor(sk, o); }
        float rq = q * rsqrtf(sq * (1.0f/HDIM) + EPSV) * qs[strm*HDIM + lane];
        float rk = k * rsqrtf(sk * (1.0f/HDIM) + EPSV) * ks[strm*HDIM + lane];

        // BUG replication: temporal stream's V is its RMS'd Q (pre-RoPE)
        float vout = (strm == 1) ? rq : v;

        float rq_p = __shfl_xor(rq, 1);
        float rk_p = __shfl_xor(rk, 1);
        float qe = (lane & 1) ? rq_p : rq;
        float qo = (lane & 1) ? rq : rq_p;
        float ke = (lane & 1) ? rk_p : rk;
        float ko = (lane & 1) ? rk : rk_p;
        const float* pel = pe + (size_t)l*128 + (lane >> 1)*4 + (lane & 1)*2;
        float qr = pel[0]*qe + pel[1]*qo;
        float kr = pel[0]*ke + pel[1]*ko;

        size_t idx = ((size_t)h * LTOT + l) * HDIM + lane;
        Q[idx] = f2bf(qr);
        K[idx] = f2bf(kr);
        vbuf[ll][lane] = f2bf(vout);
    }
    __syncthreads();
    {
        int d = tid >> 2, ls = (tid & 3) * 16;
        ushort8v u0, u1;
#pragma unroll
        for (int i = 0; i < 8; i++) u0[i] = vbuf[ls+i][d];
#pragma unroll
        for (int i = 0; i < 8; i++) u1[i] = vbuf[ls+8+i][d];
        ushort* dst = VT + ((size_t)h * 64 + d) * LTOT + l0 + ls;
        *reinterpret_cast<ushort8v*>(dst)     = u0;
        *reinterpret_cast<ushort8v*>(dst + 8) = u1;
    }
}

// ---------------- MFMA flash attention: LDS K/V dbuf + prefetch + setprio + skip-rescale ----------------
__global__ __launch_bounds__(256) void k_attn_mfma(const ushort* __restrict__ Qb,
                                                   const ushort* __restrict__ Kb,
                                                   const ushort* __restrict__ VTb,
                                                   ushort* __restrict__ att) {
    const int tid = threadIdx.x;
    const int w = tid >> 6, lane = tid & 63;
    const int h  = blockIdx.x / 36;
    const int qt = blockIdx.x % 36;
    const int qbase = qt*64 + w*16;
    const int g = lane >> 4;
    const int q = lane & 15;

    __shared__ ushort Ksl[2][64*64];
    __shared__ ushort Vsl[2][64*64];
    __shared__ ushort plds[4][1024];
    ushort* P = plds[w];

    const ushort* Kg = Kb  + (size_t)h * LTOT * 64;
    const ushort* Vg = VTb + (size_t)h * 64 * LTOT;

    const ushort* qp = Qb + ((size_t)h * LTOT + qbase + q) * 64 + g*8;
    const short8b qf0 = *reinterpret_cast<const short8b*>(qp);
    const short8b qf1 = *reinterpret_cast<const short8b*>(qp + 32);

    f32x4 out[4];
#pragma unroll
    for (int d = 0; d < 4; d++) out[d] = (f32x4){0.f,0.f,0.f,0.f};
    float m = -1e30f, lsum = 0.f;

#pragma unroll
    for (int i = 0; i < 2; i++) {
        int seg = i*256 + tid;
        int row = seg >> 3;
        int gs  = (seg & 7) ^ (row & 7);
        gload16(Kg + (size_t)row*64 + gs*8, &Ksl[0][(size_t)(i*256 + w*64)*8]);
        gload16(Vg + (size_t)row*LTOT + gs*8, &Vsl[0][(size_t)(i*256 + w*64)*8]);
    }

    for (int t = 0; t < 36; t++) {
        const int cb = t & 1;
        __syncthreads();
        if (t < 35) {
            int kvn = (t+1) * 64;
#pragma unroll
            for (int i = 0; i < 2; i++) {
                int seg = i*256 + tid;
                int row = seg >> 3;
                int gs  = (seg & 7) ^ (row & 7);
                gload16(Kg + (size_t)(kvn + row)*64 + gs*8, &Ksl[cb^1][(size_t)(i*256 + w*64)*8]);
                gload16(Vg + (size_t)row*LTOT + kvn + gs*8, &Vsl[cb^1][(size_t)(i*256 + w*64)*8]);
            }
        }

        f32x4 s[4];
        __builtin_amdgcn_s_setprio(1);
#pragma unroll
        for (int ks = 0; ks < 4; ks++) {
            int r = ks*16 + q;
            short8b kf0 = *reinterpret_cast<const short8b*>(&Ksl[cb][r*64 + ((g     ^ (r & 7)))*8]);
            short8b kf1 = *reinterpret_cast<const short8b*>(&Ksl[cb][r*64 + (((4+g) ^ (r & 7)))*8]);
            f32x4 acc = (f32x4){0.f,0.f,0.f,0.f};
            acc = __builtin_amdgcn_mfma_f32_16x16x32_bf16(kf0, qf0, acc, 0, 0, 0);
            acc = __builtin_amdgcn_mfma_f32_16x16x32_bf16(kf1, qf1, acc, 0, 0, 0);
            s[ks] = acc;
        }
        __builtin_amdgcn_s_setprio(0);

        float m0 = fmaxf(fmaxf(s[0][0], s[0][1]), s[0][2]);
        float m1 = fmaxf(fmaxf(s[0][3], s[1][0]), s[1][1]);
        float m2 = fmaxf(fmaxf(s[1][2], s[1][3]), s[2][0]);
        float m3 = fmaxf(fmaxf(s[2][1], s[2][2]), s[2][3]);
        float m4 = fmaxf(fmaxf(s[3][0], s[3][1]), s[3][2]);
        float t5 = fmaxf(fmaxf(m0, m1), m2);
        float t6 = fmaxf(fmaxf(m3, m4), s[3][3]);
        float tmax = fmaxf(t5, t6);
        tmax = fmaxf(tmax, __shfl_xor(tmax, 16));
        tmax = fmaxf(tmax, __shfl_xor(tmax, 32));
        float pm = tmax * 0.125f;
        if (!__all(pm <= m)) {
            float newm = fmaxf(m, pm);
            float c = __expf(m - newm);
            lsum *= c;
#pragma unroll
            for (int d = 0; d < 4; d++) out[d] *= c;
            m = newm;
        }
        float p[16];
        float tsum = 0.f;
#pragma unroll
        for (int ks = 0; ks < 4; ks++)
#pragma unroll
            for (int r = 0; r < 4; r++) {
                float pv = __expf(s[ks][r] * 0.125f - m);
                p[ks*4+r] = pv;
                tsum += pv;
            }
        tsum += __shfl_xor(tsum, 16);
        tsum += __shfl_xor(tsum, 32);
        lsum += tsum;

#pragma unroll
        for (int ks = 0; ks < 4; ks++) {
            ushort4v pk;
            pk.x = f2bf(p[ks*4+0]); pk.y = f2bf(p[ks*4+1]);
            pk.z = f2bf(p[ks*4+2]); pk.w = f2bf(p[ks*4+3]);
            int widx = (q*64 + ks*16 + g*4) ^ ((q & 7) << 3);
            *reinterpret_cast<ushort4v*>(&P[widx]) = pk;
        }
        __builtin_amdgcn_s_setprio(1);
#pragma unroll
        for (int c2 = 0; c2 < 2; c2++) {
            int ridx = (q*64 + c2*32 + g*8) ^ ((q & 7) << 3);
            short8b pf = *reinterpret_cast<const short8b*>(&P[ridx]);
#pragma unroll
            for (int ds = 0; ds < 4; ds++) {
                int d = ds*16 + q;
                short8b vf = *reinterpret_cast<const short8b*>(&Vsl[cb][d*64 + (((c2*4+g) ^ (d & 7)))*8]);
                out[ds] = __builtin_amdgcn_mfma_f32_16x16x32_bf16(vf, pf, out[ds], 0, 0, 0);
            }
        }
        __builtin_amdgcn_s_setprio(0);
    }

    float inv = 1.0f / lsum;
    ushort* orow = att + (size_t)(qbase + q) * DMODEL + h * HDIM;
#pragma unroll
    for (int ds = 0; ds < 4; ds++) {
        ushort4v o4;
        o4.x = f2bf(out[ds][0]*inv); o4.y = f2bf(out[ds][1]*inv);
        o4.z = f2bf(out[ds][2]*inv); o4.w = f2bf(out[ds][3]*inv);
        *reinterpret_cast<ushort4v*>(orow + ds*16 + g*4) = o4;
    }
}

// ---------------- launch ----------------
extern "C" void kernel_launch(void* const* d_in, const int* in_sizes, int n_in,
                              void* d_out, int out_size, void* d_ws, size_t ws_size,
                              hipStream_t stream) {
    const float* img  = (const float*)d_in[0];
    const float* tmp  = (const float*)d_in[1];
    const float* txt  = (const float*)d_in[2];
    const float* vec  = (const float*)d_in[3];
    const float* pe   = (const float*)d_in[4];
    const float* modw = (const float*)d_in[5];
    const float* modb = (const float*)d_in[6];
    const float* qkvw = (const float*)d_in[7];
    const float* qsc  = (const float*)d_in[8];
    const float* ksc  = (const float*)d_in[9];
    const float* projw= (const float*)d_in[10];
    const float* projb= (const float*)d_in[11];
    const float* w1   = (const float*)d_in[12];
    const float* b1   = (const float*)d_in[13];
    const float* w2   = (const float*)d_in[14];
    const float* b2   = (const float*)d_in[15];

    char* wsb = (char*)d_ws;
    float*  mod    = (float*) (wsb + MOD_OFF);
    ushort* xm     = (ushort*)(wsb + XM_OFF);
    ushort* qkv    = (ushort*)(wsb + QKV_OFF);
    ushort* t1     = (ushort*)(wsb + QKV_OFF);
    ushort* Qb     = (ushort*)(wsb + QB_OFF);
    ushort* Kb     = (ushort*)(wsb + KB_OFF);
    ushort* VTb    = (ushort*)(wsb + VTB_OFF);
    float*  p0buf  = (float*) (wsb + QB_OFF);
    float*  p1buf  = (float*) (wsb + VTB_OFF);
    float*  modp   = (float*) (wsb + ATT_OFF);
    ushort* att    = (ushort*)(wsb + ATT_OFF);
    float*  s1     = (float*) (wsb + S1_OFF);
    ushort* qkvwt  = (ushort*)(wsb + QKVWT_OFF);
    ushort* projwt = (ushort*)(wsb + PROJWT_OFF);
    ushort* w1t    = (ushort*)(wsb + W1T_OFF);

    const bool bigws = ws_size >= W2T_END;
    ushort* w2t = bigws ? (ushort*)(wsb + W2T_OFF) : w1t;   // fallback: overlay w1t

    float* out_img = (float*)d_out;
    float* out_tmp = out_img + (size_t)L_IMG * DMODEL;
    float* out_txt = out_tmp + (size_t)L_TMP * DMODEL;

    // fused conversions + mod GEMV partials
    int conv_blocks = 576 + (bigws ? 4608 : 3072);
    k_conv<<<conv_blocks, 256, 0, stream>>>(vec, modw, modp,
                                            qkvw, projw, w1, w2,
                                            qkvwt, projwt, w1t, w2t);
    k_modr<<<72, 256, 0, stream>>>(modp, modb, mod);
    k_ln_mod1<<<LTOT, 256, 0, stream>>>(img, tmp, txt, mod, xm);

    // QKV: merged dispatch, BM=128
    k_gemm_ms<0, 128, 128, ushort><<<dim3(24, 18), 256, 0, stream>>>(
        xm, xm + (size_t)256*DMODEL, xm + (size_t)1280*DMODEL,
        qkvwt, nullptr, nullptr, nullptr, nullptr, nullptr, 0,
        qkv, qkv + (size_t)256*3072, qkv + (size_t)1280*3072, 3072, DMODEL, 0);

    k_qkvfin<<<NH*36, 256, 0, stream>>>(qkv, pe, qsc, ksc, Qb, Kb, VTb);
    k_attn_mfma<<<NH*36, 256, 0, stream>>>(Qb, Kb, VTb, att);

    // proj + residual + gate1 -> s1 (BM=64: 288 blocks)
    k_gemm_ms<2, 64, 128, float><<<dim3(8, 36), 256, 0, stream>>>(
        att, att + (size_t)256*DMODEL, att + (size_t)1280*DMODEL,
        projwt, projb, txt, img, tmp, mod, 2,
        s1, s1 + (size_t)256*DMODEL, s1 + (size_t)1280*DMODEL, DMODEL, DMODEL, 0);

    // ---- phase A: txt + img MLP ----
    k_ln_modg<<<1280, 256, 0, stream>>>(s1, mod, xm);
    k_gemm_ms<1, 64, 128, ushort><<<dim3(32, 20), 256, 0, stream>>>(
        xm, xm + (size_t)256*DMODEL, xm + (size_t)1280*DMODEL,
        w1t, b1, nullptr, nullptr, nullptr, nullptr, 0,
        t1, t1 + (size_t)256*DMLP, t1, DMLP, DMODEL, 0);
    if (!bigws) {
        k_conv_slice<<<dim3(8, 64), 256, 0, stream>>>(w2,                          w1t,                          DMLP, DMODEL);
        k_conv_slice<<<dim3(8, 64), 256, 0, stream>>>(w2 + (size_t)2*DMLP*DMODEL,  w1t + (size_t)2*DMLP*DMODEL,  DMLP, DMODEL);
    }
    // mlp2 phase A: split-K=2 partials + combine
    k_gemm_ms<3, 64, 128, float><<<dim3(8, 20, 2), 256, 0, stream>>>(
        t1, t1 + (size_t)256*DMLP, t1,
        w2t, nullptr, nullptr, nullptr, nullptr, nullptr, 0,
        p0buf, p1buf, nullptr, DMODEL, DMLP, 0);
    k_mlp2fin<<<1280, 256, 0, stream>>>(p0buf, p1buf, b2, s1, mod,
                                        out_txt, out_img, out_tmp, 0);

    // ---- phase B: temporal MLP (LN input is FINAL img — reference quirk) ----
    k_ln_mod2<<<L_TMP, 256, 0, stream>>>(out_img, mod + 1*6144 + 3*1024, mod + 1*6144 + 4*1024, xm + (size_t)1280*DMODEL);
    k_gemm_ms<1, 64, 128, ushort><<<dim3(32, 16), 256, 0, stream>>>(
        xm, xm + (size_t)256*DMODEL, xm + (size_t)1280*DMODEL,
        w1t, b1, nullptr, nullptr, nullptr, nullptr, 0,
        t1, t1, t1, DMLP, DMODEL, 20);
    if (!bigws) {
        k_conv_slice<<<dim3(8, 64), 256, 0, stream>>>(w2 + (size_t)DMLP*DMODEL, w1t + (size_t)DMLP*DMODEL, DMLP, DMODEL);
    }
    // mlp2 phase B: split-K=2 partials + combine
    k_gemm_ms<3, 64, 128, float><<<dim3(8, 16, 2), 256, 0, stream>>>(
        t1, t1, t1,
        w2t, nullptr, nullptr, nullptr, nullptr, nullptr, 0,
        p0buf, p1buf, nullptr, DMODEL, DMLP, 20);
    k_mlp2fin<<<1024, 256, 0, stream>>>(p0buf, p1buf, b2, s1, mod,
                                        out_txt, out_img, out_tmp, 1280);
}

// Round 14
// 299.650 us; speedup vs baseline: 1.2449x; 1.0106x over previous
//
#include <hip/hip_runtime.h>
#include <hip/hip_bf16.h>

#define L_TXT 256
#define L_IMG 1024
#define L_TMP 1024
#define LTOT  2304
#define DMODEL 1024
#define NH 16
#define HDIM 64
#define DMLP 4096
#define EPSV 1e-6f

typedef unsigned short ushort;
typedef __attribute__((ext_vector_type(8))) short short8b;   // 8 x bf16
typedef __attribute__((ext_vector_type(8))) unsigned short ushort8v;
typedef __attribute__((ext_vector_type(4))) float f32x4;
typedef __attribute__((ext_vector_type(4))) unsigned short ushort4v;

// ---- workspace layout (bytes) ----
#define MOD_OFF    ((size_t)0)                       // f32 3*6144
#define XM_OFF     ((size_t)73728)                   // bf16 2304*1024
#define QKV_OFF    ((size_t)4792320)                 // bf16 2304*3072 (t1 overlays)
#define QB_OFF     ((size_t)18948096)                // bf16 16*2304*64 ; f32 mlp2 partial0 overlays post-attn
#define KB_OFF     ((size_t)23666688)
#define VTB_OFF    ((size_t)28385280)                // f32 mlp2 partial1 overlays post-attn
#define ATT_OFF    ((size_t)33103872)                // bf16 2304*1024 (mod partials overlay pre-attn)
#define S1_OFF     ((size_t)37822464)                // f32 2304*1024
#define QKVWT_OFF  ((size_t)49356800)                // bf16 3*3072*1024
#define PROJWT_OFF ((size_t)68231168)                // bf16 3*1024*1024
#define W1T_OFF    ((size_t)74522624)                // bf16 3*4096*1024
#define W2T_OFF    ((size_t)99688448)                // bf16 3*1024*4096 (if ws large)
#define W2T_END    ((size_t)124854272)

static __device__ __forceinline__ ushort f2bf(float x) {
    __hip_bfloat16 b = __float2bfloat16(x);
    return *reinterpret_cast<ushort*>(&b);
}
static __device__ __forceinline__ float bf2f(ushort u) {
    return __uint_as_float(((unsigned)u) << 16);
}

typedef __attribute__((address_space(1))) const unsigned char gas_t;
typedef __attribute__((address_space(3))) unsigned char las_t;
static __device__ __forceinline__ void gload16(const void* g, void* l) {
    __builtin_amdgcn_global_load_lds((gas_t*)g, (las_t*)l, 16, 0, 0);
}

// ---- conv tile body (f32 [K][N] -> bf16 [N][K], 64k x 128n) ----
static __device__ __forceinline__ void conv_tile(const float* __restrict__ W,
                                                 ushort* __restrict__ WT,
                                                 int K, int N, int nt, int kt,
                                                 float (*tb)[132], int tid) {
    {
        int r = tid >> 5, c4 = (tid & 31) * 4;
#pragma unroll
        for (int i = 0; i < 8; i++) {
            float4 v = *reinterpret_cast<const float4*>(W + (size_t)(kt*64 + r + i*8) * N + nt*128 + c4);
            tb[r + i*8][c4+0] = v.x; tb[r + i*8][c4+1] = v.y;
            tb[r + i*8][c4+2] = v.z; tb[r + i*8][c4+3] = v.w;
        }
    }
    __syncthreads();
    {
        int n = tid >> 1, k32 = (tid & 1) * 32;
        ushort* dst = WT + (size_t)(nt*128 + n) * K + kt*64 + k32;
#pragma unroll
        for (int j2 = 0; j2 < 4; j2++) {
            ushort8v u;
#pragma unroll
            for (int i = 0; i < 8; i++) u[i] = f2bf(tb[k32 + j2*8 + i][n]);
            *reinterpret_cast<ushort8v*>(dst + j2*8) = u;
        }
    }
}

// ---------------- fused: mod GEMV partials (576) + all weight transpose tiles ----------------
__global__ __launch_bounds__(256) void k_conv(const float* __restrict__ vec,
                                              const float* __restrict__ modw,
                                              float* __restrict__ modp,
                                              const float* __restrict__ qkvw,
                                              const float* __restrict__ projw,
                                              const float* __restrict__ w1,
                                              const float* __restrict__ w2,
                                              ushort* __restrict__ qkvwt,
                                              ushort* __restrict__ projwt,
                                              ushort* __restrict__ w1t,
                                              ushort* __restrict__ w2t) {
    __shared__ float tb[64][132];
    int bid = blockIdx.x;
    int tid = threadIdx.x;
    if (bid < 576) {
        // ---- mod GEMV partial: K-slice of 256, dual accumulator chains ----
        float* svs = &tb[0][0];             // 256 floats
        float* pl  = &tb[0][0] + 256;       // 8 x 128
        int g0 = (bid >> 2) * 128;
        int ks = bid & 3;
        int i  = g0 / 6144;
        int j0 = g0 - i * 6144;
        {
            float v = vec[ks*256 + tid];
            svs[tid] = v / (1.0f + __expf(-v));
        }
        __syncthreads();
        int jl = tid & 31, ko = tid >> 5;
        const float* wp = modw + (size_t)i * 1024 * 6144 + (size_t)(ks*256) * 6144 + j0 + jl*4;
        float a0x=0.f,a0y=0.f,a0z=0.f,a0w=0.f;
        float a1x=0.f,a1y=0.f,a1z=0.f,a1w=0.f;
#pragma unroll 4
        for (int kk = 0; kk < 16; kk++) {
            int k0 = kk*16 + ko;
            int k1 = k0 + 8;
            float4 w0 = *reinterpret_cast<const float4*>(wp + (size_t)k0 * 6144);
            float4 w1v = *reinterpret_cast<const float4*>(wp + (size_t)k1 * 6144);
            float s0 = svs[k0], s1 = svs[k1];
            a0x += s0*w0.x; a0y += s0*w0.y; a0z += s0*w0.z; a0w += s0*w0.w;
            a1x += s1*w1v.x; a1y += s1*w1v.y; a1z += s1*w1v.z; a1w += s1*w1v.w;
        }
        pl[ko*128 + jl*4+0] = a0x + a1x;
        pl[ko*128 + jl*4+1] = a0y + a1y;
        pl[ko*128 + jl*4+2] = a0z + a1z;
        pl[ko*128 + jl*4+3] = a0w + a1w;
        __syncthreads();
        if (tid < 128) {
            float s = 0.f;
#pragma unroll
            for (int k = 0; k < 8; k++) s += pl[k*128 + tid];
            modp[(size_t)ks*18432 + g0 + tid] = s;
        }
        return;
    }
    int b = bid - 576;
    if (b < 1152) {                 // qkv: K=1024, N=3072 -> 16 x 24 tiles per s
        int s = b / 384, r = b % 384;
        conv_tile(qkvw + (size_t)s * 1024 * 3072, qkvwt + (size_t)s * 3072 * 1024,
                  1024, 3072, r % 24, r / 24, tb, tid);
    } else if (b < 1536) {          // proj: 16 x 8
        b -= 1152; int s = b / 128, r = b % 128;
        conv_tile(projw + (size_t)s * 1024 * 1024, projwt + (size_t)s * 1024 * 1024,
                  1024, 1024, r % 8, r / 8, tb, tid);
    } else if (b < 3072) {          // w1: 16 x 32
        b -= 1536; int s = b / 512, r = b % 512;
        conv_tile(w1 + (size_t)s * 1024 * 4096, w1t + (size_t)s * 4096 * 1024,
                  1024, 4096, r % 32, r / 32, tb, tid);
    } else {                        // w2: K=4096, N=1024 -> 64 x 8 (bigws only)
        b -= 3072; int s = b / 512, r = b % 512;
        conv_tile(w2 + (size_t)s * 4096 * 1024, w2t + (size_t)s * 1024 * 4096,
                  4096, 1024, r % 8, r / 8, tb, tid);
    }
}

// mod partial reduce
__global__ __launch_bounds__(256) void k_modr(const float* __restrict__ p,
                                              const float* __restrict__ modb,
                                              float* __restrict__ mod) {
    int g = blockIdx.x * 256 + threadIdx.x;
    float s = p[g] + p[18432 + g] + p[2*18432 + g] + p[3*18432 + g];
    mod[g] = s + modb[g];
}

// standalone slice transpose (w2 fallback): grid (N/128, K/64)
__global__ __launch_bounds__(256) void k_conv_slice(const float* __restrict__ W,
                                                    ushort* __restrict__ WT,
                                                    int K, int N) {
    __shared__ float tb[64][132];
    conv_tile(W, WT, K, N, blockIdx.x, blockIdx.y, tb, threadIdx.x);
}

// ---------------- LN + (1+sc)*x + sh -> bf16, stream-select (inputs) ----------------
__global__ __launch_bounds__(256) void k_ln_mod1(const float* __restrict__ img,
                                                 const float* __restrict__ tmp,
                                                 const float* __restrict__ txt,
                                                 const float* __restrict__ mod,
                                                 ushort* __restrict__ xm) {
    int l = blockIdx.x;
    const float* src; int strm;
    if (l < L_TXT)              { src = txt + (size_t)l * DMODEL;            strm = 2; }
    else if (l < L_TXT + L_IMG) { src = img + (size_t)(l - L_TXT) * DMODEL;  strm = 0; }
    else                        { src = tmp + (size_t)(l - L_TXT - L_IMG) * DMODEL; strm = 1; }

    int d = threadIdx.x * 4;
    float4 x = *reinterpret_cast<const float4*>(src + d);
    float s  = x.x + x.y + x.z + x.w;
    float s2 = x.x*x.x + x.y*x.y + x.z*x.z + x.w*x.w;
#pragma unroll
    for (int o = 32; o > 0; o >>= 1) { s += __shfl_xor(s, o); s2 += __shfl_xor(s2, o); }
    __shared__ float red[8];
    int wave = threadIdx.x >> 6, lane = threadIdx.x & 63;
    if (lane == 0) { red[wave*2] = s; red[wave*2+1] = s2; }
    __syncthreads();
    if (threadIdx.x == 0) {
        float a = 0.f, b = 0.f;
        for (int w = 0; w < 4; w++) { a += red[w*2]; b += red[w*2+1]; }
        red[0] = a; red[1] = b;
    }
    __syncthreads();
    float mean = red[0] * (1.0f/DMODEL);
    float var  = red[1] * (1.0f/DMODEL) - mean*mean;
    float inv  = rsqrtf(var + EPSV);

    const float* sh = mod + strm*6144;
    const float* sc = sh + 1024;
    float4 shv = *reinterpret_cast<const float4*>(sh + d);
    float4 scv = *reinterpret_cast<const float4*>(sc + d);
    ushort4v o;
    o.x = f2bf((1.f+scv.x)*((x.x-mean)*inv) + shv.x);
    o.y = f2bf((1.f+scv.y)*((x.y-mean)*inv) + shv.y);
    o.z = f2bf((1.f+scv.z)*((x.z-mean)*inv) + shv.z);
    o.w = f2bf((1.f+scv.w)*((x.w-mean)*inv) + shv.w);
    *reinterpret_cast<ushort4v*>(xm + (size_t)l*DMODEL + d) = o;
}

// ---------------- generic LN + modulate -> bf16 (explicit pointers) ----------------
__global__ __launch_bounds__(256) void k_ln_mod2(const float* __restrict__ src,
                                                 const float* __restrict__ sh,
                                                 const float* __restrict__ sc,
                                                 ushort* __restrict__ out) {
    int r = blockIdx.x;
    const float* srow = src + (size_t)r * DMODEL;
    int d = threadIdx.x * 4;
    float4 x = *reinterpret_cast<const float4*>(srow + d);
    float s  = x.x + x.y + x.z + x.w;
    float s2 = x.x*x.x + x.y*x.y + x.z*x.z + x.w*x.w;
#pragma unroll
    for (int o = 32; o > 0; o >>= 1) { s += __shfl_xor(s, o); s2 += __shfl_xor(s2, o); }
    __shared__ float red[8];
    int wave = threadIdx.x >> 6, lane = threadIdx.x & 63;
    if (lane == 0) { red[wave*2] = s; red[wave*2+1] = s2; }
    __syncthreads();
    if (threadIdx.x == 0) {
        float a = 0.f, b = 0.f;
        for (int w = 0; w < 4; w++) { a += red[w*2]; b += red[w*2+1]; }
        red[0] = a; red[1] = b;
    }
    __syncthreads();
    float mean = red[0] * (1.0f/DMODEL);
    float var  = red[1] * (1.0f/DMODEL) - mean*mean;
    float inv  = rsqrtf(var + EPSV);
    float4 shv = *reinterpret_cast<const float4*>(sh + d);
    float4 scv = *reinterpret_cast<const float4*>(sc + d);
    ushort4v o;
    o.x = f2bf((1.f+scv.x)*((x.x-mean)*inv) + shv.x);
    o.y = f2bf((1.f+scv.y)*((x.y-mean)*inv) + shv.y);
    o.z = f2bf((1.f+scv.z)*((x.z-mean)*inv) + shv.z);
    o.w = f2bf((1.f+scv.w)*((x.w-mean)*inv) + shv.w);
    *reinterpret_cast<ushort4v*>(out + (size_t)r*DMODEL + d) = o;
}

// ---------------- phase-A LN: global rows 0..1279 of s1 (txt then img) ----------------
__global__ __launch_bounds__(256) void k_ln_modg(const float* __restrict__ s1,
                                                 const float* __restrict__ mod,
                                                 ushort* __restrict__ xm) {
    int row = blockIdx.x;
    int strm = row < 256 ? 2 : 0;
    const float* srow = s1 + (size_t)row * DMODEL;
    int d = threadIdx.x * 4;
    float4 x = *reinterpret_cast<const float4*>(srow + d);
    float s  = x.x + x.y + x.z + x.w;
    float s2 = x.x*x.x + x.y*x.y + x.z*x.z + x.w*x.w;
#pragma unroll
    for (int o = 32; o > 0; o >>= 1) { s += __shfl_xor(s, o); s2 += __shfl_xor(s2, o); }
    __shared__ float red[8];
    int wave = threadIdx.x >> 6, lane = threadIdx.x & 63;
    if (lane == 0) { red[wave*2] = s; red[wave*2+1] = s2; }
    __syncthreads();
    if (threadIdx.x == 0) {
        float a = 0.f, b = 0.f;
        for (int w = 0; w < 4; w++) { a += red[w*2]; b += red[w*2+1]; }
        red[0] = a; red[1] = b;
    }
    __syncthreads();
    float mean = red[0] * (1.0f/DMODEL);
    float var  = red[1] * (1.0f/DMODEL) - mean*mean;
    float inv  = rsqrtf(var + EPSV);
    const float* sh = mod + strm*6144 + 3*1024;
    const float* sc = mod + strm*6144 + 4*1024;
    float4 shv = *reinterpret_cast<const float4*>(sh + d);
    float4 scv = *reinterpret_cast<const float4*>(sc + d);
    ushort4v o;
    o.x = f2bf((1.f+scv.x)*((x.x-mean)*inv) + shv.x);
    o.y = f2bf((1.f+scv.y)*((x.y-mean)*inv) + shv.y);
    o.z = f2bf((1.f+scv.z)*((x.z-mean)*inv) + shv.z);
    o.w = f2bf((1.f+scv.w)*((x.w-mean)*inv) + shv.w);
    *reinterpret_cast<ushort4v*>(xm + (size_t)row*DMODEL + d) = o;
}

// ---------------- multi-stream bf16 MFMA GEMM, templated BM/BN, BK=64 ----------------
// MODE 0: C=A@W(+b) bf16   MODE 1: gelu (XCD-swizzled)   MODE 2: res+gate*(...)   MODE 3: split-K f32 partial
__device__ __forceinline__ float gelu_fast(float x) {
    return x / (1.0f + __expf(-1.5957691216057308f * (x + 0.044715f * x * x * x)));
}

template<int MODE, int BM, int BN, typename OutT>
__global__ __launch_bounds__(256) void k_gemm_ms(const ushort* __restrict__ A_t,
                                                 const ushort* __restrict__ A_i,
                                                 const ushort* __restrict__ A_m,
                                                 const ushort* __restrict__ BT,
                                                 const float* __restrict__ bias,
                                                 const float* __restrict__ res_t,
                                                 const float* __restrict__ res_i,
                                                 const float* __restrict__ res_m,
                                                 const float* __restrict__ mod, int gidx,
                                                 OutT* __restrict__ out_t,
                                                 OutT* __restrict__ out_i,
                                                 OutT* __restrict__ out_m,
                                                 int N, int K, int ry0) {
    constexpr int MI = BM / 32;
    constexpr int NI = BN / 32;

    int bx = blockIdx.x, by = blockIdx.y;
    if (MODE == 1) {
        // XCD-chunked swizzle (bijective; gridDim.x must be a multiple of 8):
        // flat f -> nx = (f/ (8*NY))*8 + f%8, ny = (f/8) % NY  => XCD(f)=f%8 == nx%8
        int f = by * gridDim.x + bx;
        int nxm8 = f & 7;
        int rest = f >> 3;
        int ny = rest % gridDim.y;
        int nxd8 = rest / gridDim.y;
        bx = nxd8 * 8 + nxm8;
        by = ny;
    }

    const int brow = (ry0 + by) * BM;
    int s, lrow;
    if (brow < 256)       { s = 2; lrow = brow; }
    else if (brow < 1280) { s = 0; lrow = brow - 256; }
    else                  { s = 1; lrow = brow - 1280; }

    const ushort* A = (s==2 ? A_t : s==0 ? A_i : A_m) + (size_t)lrow * K;
    const ushort* BTs = BT + (size_t)s * N * K;
    const float* bi = (MODE != 3 && bias) ? bias + (size_t)s * N : nullptr;
    const float* resl = (MODE==2) ? ((s==2 ? res_t : s==0 ? res_i : res_m) + (size_t)lrow * N) : nullptr;
    const float* gate = (MODE==2) ? (mod + s*6144 + gidx*1024) : nullptr;
    OutT* Cl;
    if (MODE == 3) Cl = (blockIdx.z == 0 ? out_t : out_i) + (size_t)brow * N;
    else           Cl = (s==2 ? out_t : s==0 ? out_i : out_m) + (size_t)lrow * N;

    const int kbeg = (MODE == 3) ? blockIdx.z * (K >> 1) : 0;
    const int kend = (MODE == 3) ? kbeg + (K >> 1) : K;

    __shared__ ushort Asl[BM*64];
    __shared__ ushort Bsl[BN*64];
    const int tid = threadIdx.x;
    const int lane = tid & 63, w = tid >> 6;
    const int wr = w >> 1, wc = w & 1;
    const int bn = bx * BN;
    const int r15 = lane & 15, g4 = lane >> 4;

    f32x4 acc[MI][NI];
#pragma unroll
    for (int i = 0; i < MI; i++)
#pragma unroll
        for (int j = 0; j < NI; j++) acc[i][j] = (f32x4){0.f,0.f,0.f,0.f};

    for (int k0 = kbeg; k0 < kend; k0 += 64) {
#pragma unroll
        for (int i = 0; i < BM/32; i++) {
            int chunk = i*4 + w;
            int seg = chunk*64 + lane;
            int row = seg >> 3;
            int gs  = (seg & 7) ^ (row & 7);
            gload16(A + (size_t)row * K + k0 + gs*8, Asl + (size_t)chunk * 512);
        }
#pragma unroll
        for (int i = 0; i < BN/32; i++) {
            int chunk = i*4 + w;
            int seg = chunk*64 + lane;
            int row = seg >> 3;
            int gs  = (seg & 7) ^ (row & 7);
            gload16(BTs + (size_t)(bn + row) * K + k0 + gs*8, Bsl + (size_t)chunk * 512);
        }
        __syncthreads();
#pragma unroll
        for (int kk = 0; kk < 2; kk++) {
            short8b a[MI], b[NI];
#pragma unroll
            for (int mi = 0; mi < MI; mi++) {
                int row = wr*(MI*16) + mi*16 + r15;
                int c   = kk*4 + g4;
                a[mi] = *reinterpret_cast<const short8b*>(&Asl[row*64 + ((c ^ (row & 7)))*8]);
            }
#pragma unroll
            for (int ni = 0; ni < NI; ni++) {
                int row = wc*(NI*16) + ni*16 + r15;
                int c   = kk*4 + g4;
                b[ni] = *reinterpret_cast<const short8b*>(&Bsl[row*64 + ((c ^ (row & 7)))*8]);
            }
#pragma unroll
            for (int mi = 0; mi < MI; mi++)
#pragma unroll
                for (int ni = 0; ni < NI; ni++)
                    acc[mi][ni] = __builtin_amdgcn_mfma_f32_16x16x32_bf16(a[mi], b[ni], acc[mi][ni], 0, 0, 0);
        }
        __syncthreads();
    }

#pragma unroll
    for (int mi = 0; mi < MI; mi++) {
#pragma unroll
        for (int ni = 0; ni < NI; ni++) {
            int col = bn + wc*(NI*16) + ni*16 + r15;
            float bv = bi ? bi[col] : 0.f;
#pragma unroll
            for (int r = 0; r < 4; r++) {
                int rr = wr*(MI*16) + mi*16 + g4*4 + r;
                float v = acc[mi][ni][r] + bv;
                if (MODE == 1) v = gelu_fast(v);
                if (MODE == 2) v = resl[(size_t)rr * N + col] + gate[col] * v;
                if (sizeof(OutT) == 2) Cl[(size_t)rr * N + col] = (OutT)f2bf(v);
                else                   Cl[(size_t)rr * N + col] = (OutT)v;
            }
        }
    }
}

// ---------------- mlp2 split-K combine: out = res + gate*(p0+p1+b2) ----------------
__global__ __launch_bounds__(256) void k_mlp2fin(const float* __restrict__ p0,
                                                 const float* __restrict__ p1,
                                                 const float* __restrict__ b2,
                                                 const float* __restrict__ s1,
                                                 const float* __restrict__ mod,
                                                 float* __restrict__ out_t,
                                                 float* __restrict__ out_i,
                                                 float* __restrict__ out_m,
                                                 int row0) {
    int row = row0 + blockIdx.x;
    int s, lrow;
    if (row < 256)       { s = 2; lrow = row; }
    else if (row < 1280) { s = 0; lrow = row - 256; }
    else                 { s = 1; lrow = row - 1280; }
    const float* gate = mod + s*6144 + 5*1024;
    const float* bias = b2 + s*1024;
    float* outp = (s==2 ? out_t : s==0 ? out_i : out_m) + (size_t)lrow * DMODEL;
    int d = threadIdx.x * 4;
    float4 a = *reinterpret_cast<const float4*>(p0 + (size_t)row*DMODEL + d);
    float4 b = *reinterpret_cast<const float4*>(p1 + (size_t)row*DMODEL + d);
    float4 r = *reinterpret_cast<const float4*>(s1 + (size_t)row*DMODEL + d);
    float4 g = *reinterpret_cast<const float4*>(gate + d);
    float4 bi = *reinterpret_cast<const float4*>(bias + d);
    float4 o;
    o.x = r.x + g.x*(a.x + b.x + bi.x);
    o.y = r.y + g.y*(a.y + b.y + bi.y);
    o.z = r.z + g.z*(a.z + b.z + bi.z);
    o.w = r.w + g.w*(a.w + b.w + bi.w);
    *reinterpret_cast<float4*>(outp + d) = o;
}

// ---------------- qkv finalize + V transpose: block = (h, 64-l tile) ----------------
__global__ __launch_bounds__(256) void k_qkvfin(const ushort* __restrict__ qkv,
                                                const float* __restrict__ pe,
                                                const float* __restrict__ qs,
                                                const float* __restrict__ ks,
                                                ushort* __restrict__ Q,
                                                ushort* __restrict__ K,
                                                ushort* __restrict__ VT) {
    const int tid = threadIdx.x;
    const int w = tid >> 6, lane = tid & 63;
    const int h  = blockIdx.x / 36;
    const int l0 = (blockIdx.x % 36) * 64;
    __shared__ ushort vbuf[64][65];

    for (int it = 0; it < 16; it++) {
        int ll = it*4 + w;
        int l = l0 + ll;
        int strm;
        if (l < L_TXT) strm = 2; else if (l < L_TXT + L_IMG) strm = 0; else strm = 1;
        const ushort* row = qkv + (size_t)l * 3 * DMODEL + h*HDIM + lane;
        float q = bf2f(row[0]);
        float k = bf2f(row[DMODEL]);
        float v = bf2f(row[2*DMODEL]);

        float sq = q*q, sk = k*k;
#pragma unroll
        for (int o = 32; o > 0; o >>= 1) { sq += __shfl_xor(sq, o); sk += __shfl_xor(sk, o); }
        float rq = q * rsqrtf(sq * (1.0f/HDIM) + EPSV) * qs[strm*HDIM + lane];
        float rk = k * rsqrtf(sk * (1.0f/HDIM) + EPSV) * ks[strm*HDIM + lane];

        // BUG replication: temporal stream's V is its RMS'd Q (pre-RoPE)
        float vout = (strm == 1) ? rq : v;

        float rq_p = __shfl_xor(rq, 1);
        float rk_p = __shfl_xor(rk, 1);
        float qe = (lane & 1) ? rq_p : rq;
        float qo = (lane & 1) ? rq : rq_p;
        float ke = (lane & 1) ? rk_p : rk;
        float ko = (lane & 1) ? rk : rk_p;
        const float* pel = pe + (size_t)l*128 + (lane >> 1)*4 + (lane & 1)*2;
        float qr = pel[0]*qe + pel[1]*qo;
        float kr = pel[0]*ke + pel[1]*ko;

        size_t idx = ((size_t)h * LTOT + l) * HDIM + lane;
        Q[idx] = f2bf(qr);
        K[idx] = f2bf(kr);
        vbuf[ll][lane] = f2bf(vout);
    }
    __syncthreads();
    {
        int d = tid >> 2, ls = (tid & 3) * 16;
        ushort8v u0, u1;
#pragma unroll
        for (int i = 0; i < 8; i++) u0[i] = vbuf[ls+i][d];
#pragma unroll
        for (int i = 0; i < 8; i++) u1[i] = vbuf[ls+8+i][d];
        ushort* dst = VT + ((size_t)h * 64 + d) * LTOT + l0 + ls;
        *reinterpret_cast<ushort8v*>(dst)     = u0;
        *reinterpret_cast<ushort8v*>(dst + 8) = u1;
    }
}

// ---------------- MFMA flash attention: LDS K/V dbuf + prefetch + setprio + skip-rescale ----------------
__global__ __launch_bounds__(256) void k_attn_mfma(const ushort* __restrict__ Qb,
                                                   const ushort* __restrict__ Kb,
                                                   const ushort* __restrict__ VTb,
                                                   ushort* __restrict__ att) {
    const int tid = threadIdx.x;
    const int w = tid >> 6, lane = tid & 63;
    const int h  = blockIdx.x / 36;
    const int qt = blockIdx.x % 36;
    const int qbase = qt*64 + w*16;
    const int g = lane >> 4;
    const int q = lane & 15;

    __shared__ ushort Ksl[2][64*64];
    __shared__ ushort Vsl[2][64*64];
    __shared__ ushort plds[4][1024];
    ushort* P = plds[w];

    const ushort* Kg = Kb  + (size_t)h * LTOT * 64;
    const ushort* Vg = VTb + (size_t)h * 64 * LTOT;

    const ushort* qp = Qb + ((size_t)h * LTOT + qbase + q) * 64 + g*8;
    const short8b qf0 = *reinterpret_cast<const short8b*>(qp);
    const short8b qf1 = *reinterpret_cast<const short8b*>(qp + 32);

    f32x4 out[4];
#pragma unroll
    for (int d = 0; d < 4; d++) out[d] = (f32x4){0.f,0.f,0.f,0.f};
    float m = -1e30f, lsum = 0.f;

#pragma unroll
    for (int i = 0; i < 2; i++) {
        int seg = i*256 + tid;
        int row = seg >> 3;
        int gs  = (seg & 7) ^ (row & 7);
        gload16(Kg + (size_t)row*64 + gs*8, &Ksl[0][(size_t)(i*256 + w*64)*8]);
        gload16(Vg + (size_t)row*LTOT + gs*8, &Vsl[0][(size_t)(i*256 + w*64)*8]);
    }

    for (int t = 0; t < 36; t++) {
        const int cb = t & 1;
        __syncthreads();
        if (t < 35) {
            int kvn = (t+1) * 64;
#pragma unroll
            for (int i = 0; i < 2; i++) {
                int seg = i*256 + tid;
                int row = seg >> 3;
                int gs  = (seg & 7) ^ (row & 7);
                gload16(Kg + (size_t)(kvn + row)*64 + gs*8, &Ksl[cb^1][(size_t)(i*256 + w*64)*8]);
                gload16(Vg + (size_t)row*LTOT + kvn + gs*8, &Vsl[cb^1][(size_t)(i*256 + w*64)*8]);
            }
        }

        f32x4 s[4];
        __builtin_amdgcn_s_setprio(1);
#pragma unroll
        for (int ks = 0; ks < 4; ks++) {
            int r = ks*16 + q;
            short8b kf0 = *reinterpret_cast<const short8b*>(&Ksl[cb][r*64 + ((g     ^ (r & 7)))*8]);
            short8b kf1 = *reinterpret_cast<const short8b*>(&Ksl[cb][r*64 + (((4+g) ^ (r & 7)))*8]);
            f32x4 acc = (f32x4){0.f,0.f,0.f,0.f};
            acc = __builtin_amdgcn_mfma_f32_16x16x32_bf16(kf0, qf0, acc, 0, 0, 0);
            acc = __builtin_amdgcn_mfma_f32_16x16x32_bf16(kf1, qf1, acc, 0, 0, 0);
            s[ks] = acc;
        }
        __builtin_amdgcn_s_setprio(0);

        float m0 = fmaxf(fmaxf(s[0][0], s[0][1]), s[0][2]);
        float m1 = fmaxf(fmaxf(s[0][3], s[1][0]), s[1][1]);
        float m2 = fmaxf(fmaxf(s[1][2], s[1][3]), s[2][0]);
        float m3 = fmaxf(fmaxf(s[2][1], s[2][2]), s[2][3]);
        float m4 = fmaxf(fmaxf(s[3][0], s[3][1]), s[3][2]);
        float t5 = fmaxf(fmaxf(m0, m1), m2);
        float t6 = fmaxf(fmaxf(m3, m4), s[3][3]);
        float tmax = fmaxf(t5, t6);
        tmax = fmaxf(tmax, __shfl_xor(tmax, 16));
        tmax = fmaxf(tmax, __shfl_xor(tmax, 32));
        float pm = tmax * 0.125f;
        if (!__all(pm <= m)) {
            float newm = fmaxf(m, pm);
            float c = __expf(m - newm);
            lsum *= c;
#pragma unroll
            for (int d = 0; d < 4; d++) out[d] *= c;
            m = newm;
        }
        float p[16];
        float tsum = 0.f;
#pragma unroll
        for (int ks = 0; ks < 4; ks++)
#pragma unroll
            for (int r = 0; r < 4; r++) {
                float pv = __expf(s[ks][r] * 0.125f - m);
                p[ks*4+r] = pv;
                tsum += pv;
            }
        tsum += __shfl_xor(tsum, 16);
        tsum += __shfl_xor(tsum, 32);
        lsum += tsum;

#pragma unroll
        for (int ks = 0; ks < 4; ks++) {
            ushort4v pk;
            pk.x = f2bf(p[ks*4+0]); pk.y = f2bf(p[ks*4+1]);
            pk.z = f2bf(p[ks*4+2]); pk.w = f2bf(p[ks*4+3]);
            int widx = (q*64 + ks*16 + g*4) ^ ((q & 7) << 3);
            *reinterpret_cast<ushort4v*>(&P[widx]) = pk;
        }
        __builtin_amdgcn_s_setprio(1);
#pragma unroll
        for (int c2 = 0; c2 < 2; c2++) {
            int ridx = (q*64 + c2*32 + g*8) ^ ((q & 7) << 3);
            short8b pf = *reinterpret_cast<const short8b*>(&P[ridx]);
#pragma unroll
            for (int ds = 0; ds < 4; ds++) {
                int d = ds*16 + q;
                short8b vf = *reinterpret_cast<const short8b*>(&Vsl[cb][d*64 + (((c2*4+g) ^ (d & 7)))*8]);
                out[ds] = __builtin_amdgcn_mfma_f32_16x16x32_bf16(vf, pf, out[ds], 0, 0, 0);
            }
        }
        __builtin_amdgcn_s_setprio(0);
    }

    float inv = 1.0f / lsum;
    ushort* orow = att + (size_t)(qbase + q) * DMODEL + h * HDIM;
#pragma unroll
    for (int ds = 0; ds < 4; ds++) {
        ushort4v o4;
        o4.x = f2bf(out[ds][0]*inv); o4.y = f2bf(out[ds][1]*inv);
        o4.z = f2bf(out[ds][2]*inv); o4.w = f2bf(out[ds][3]*inv);
        *reinterpret_cast<ushort4v*>(orow + ds*16 + g*4) = o4;
    }
}

// ---------------- launch ----------------
extern "C" void kernel_launch(void* const* d_in, const int* in_sizes, int n_in,
                              void* d_out, int out_size, void* d_ws, size_t ws_size,
                              hipStream_t stream) {
    const float* img  = (const float*)d_in[0];
    const float* tmp  = (const float*)d_in[1];
    const float* txt  = (const float*)d_in[2];
    const float* vec  = (const float*)d_in[3];
    const float* pe   = (const float*)d_in[4];
    const float* modw = (const float*)d_in[5];
    const float* modb = (const float*)d_in[6];
    const float* qkvw = (const float*)d_in[7];
    const float* qsc  = (const float*)d_in[8];
    const float* ksc  = (const float*)d_in[9];
    const float* projw= (const float*)d_in[10];
    const float* projb= (const float*)d_in[11];
    const float* w1   = (const float*)d_in[12];
    const float* b1   = (const float*)d_in[13];
    const float* w2   = (const float*)d_in[14];
    const float* b2   = (const float*)d_in[15];

    char* wsb = (char*)d_ws;
    float*  mod    = (float*) (wsb + MOD_OFF);
    ushort* xm     = (ushort*)(wsb + XM_OFF);
    ushort* qkv    = (ushort*)(wsb + QKV_OFF);
    ushort* t1     = (ushort*)(wsb + QKV_OFF);
    ushort* Qb     = (ushort*)(wsb + QB_OFF);
    ushort* Kb     = (ushort*)(wsb + KB_OFF);
    ushort* VTb    = (ushort*)(wsb + VTB_OFF);
    float*  p0buf  = (float*) (wsb + QB_OFF);
    float*  p1buf  = (float*) (wsb + VTB_OFF);
    float*  modp   = (float*) (wsb + ATT_OFF);
    ushort* att    = (ushort*)(wsb + ATT_OFF);
    float*  s1     = (float*) (wsb + S1_OFF);
    ushort* qkvwt  = (ushort*)(wsb + QKVWT_OFF);
    ushort* projwt = (ushort*)(wsb + PROJWT_OFF);
    ushort* w1t    = (ushort*)(wsb + W1T_OFF);

    const bool bigws = ws_size >= W2T_END;
    ushort* w2t = bigws ? (ushort*)(wsb + W2T_OFF) : w1t;   // fallback: overlay w1t

    float* out_img = (float*)d_out;
    float* out_tmp = out_img + (size_t)L_IMG * DMODEL;
    float* out_txt = out_tmp + (size_t)L_TMP * DMODEL;

    // fused conversions + mod GEMV partials
    int conv_blocks = 576 + (bigws ? 4608 : 3072);
    k_conv<<<conv_blocks, 256, 0, stream>>>(vec, modw, modp,
                                            qkvw, projw, w1, w2,
                                            qkvwt, projwt, w1t, w2t);
    k_modr<<<72, 256, 0, stream>>>(modp, modb, mod);
    k_ln_mod1<<<LTOT, 256, 0, stream>>>(img, tmp, txt, mod, xm);

    // QKV: merged dispatch, BM=64 (864 blocks)
    k_gemm_ms<0, 64, 128, ushort><<<dim3(24, 36), 256, 0, stream>>>(
        xm, xm + (size_t)256*DMODEL, xm + (size_t)1280*DMODEL,
        qkvwt, nullptr, nullptr, nullptr, nullptr, nullptr, 0,
        qkv, qkv + (size_t)256*3072, qkv + (size_t)1280*3072, 3072, DMODEL, 0);

    k_qkvfin<<<NH*36, 256, 0, stream>>>(qkv, pe, qsc, ksc, Qb, Kb, VTb);
    k_attn_mfma<<<NH*36, 256, 0, stream>>>(Qb, Kb, VTb, att);

    // proj + residual + gate1 -> s1 (BM=64, BN=64: 576 blocks)
    k_gemm_ms<2, 64, 64, float><<<dim3(16, 36), 256, 0, stream>>>(
        att, att + (size_t)256*DMODEL, att + (size_t)1280*DMODEL,
        projwt, projb, txt, img, tmp, mod, 2,
        s1, s1 + (size_t)256*DMODEL, s1 + (size_t)1280*DMODEL, DMODEL, DMODEL, 0);

    // ---- phase A: txt + img MLP ----
    k_ln_modg<<<1280, 256, 0, stream>>>(s1, mod, xm);
    k_gemm_ms<1, 64, 128, ushort><<<dim3(32, 20), 256, 0, stream>>>(
        xm, xm + (size_t)256*DMODEL, xm + (size_t)1280*DMODEL,
        w1t, b1, nullptr, nullptr, nullptr, nullptr, 0,
        t1, t1 + (size_t)256*DMLP, t1, DMLP, DMODEL, 0);
    if (!bigws) {
        k_conv_slice<<<dim3(8, 64), 256, 0, stream>>>(w2,                          w1t,                          DMLP, DMODEL);
        k_conv_slice<<<dim3(8, 64), 256, 0, stream>>>(w2 + (size_t)2*DMLP*DMODEL,  w1t + (size_t)2*DMLP*DMODEL,  DMLP, DMODEL);
    }
    // mlp2 phase A: split-K=2 partials + combine
    k_gemm_ms<3, 64, 128, float><<<dim3(8, 20, 2), 256, 0, stream>>>(
        t1, t1 + (size_t)256*DMLP, t1,
        w2t, nullptr, nullptr, nullptr, nullptr, nullptr, 0,
        p0buf, p1buf, nullptr, DMODEL, DMLP, 0);
    k_mlp2fin<<<1280, 256, 0, stream>>>(p0buf, p1buf, b2, s1, mod,
                                        out_txt, out_img, out_tmp, 0);

    // ---- phase B: temporal MLP (LN input is FINAL img — reference quirk) ----
    k_ln_mod2<<<L_TMP, 256, 0, stream>>>(out_img, mod + 1*6144 + 3*1024, mod + 1*6144 + 4*1024, xm + (size_t)1280*DMODEL);
    k_gemm_ms<1, 64, 128, ushort><<<dim3(32, 16), 256, 0, stream>>>(
        xm, xm + (size_t)256*DMODEL, xm + (size_t)1280*DMODEL,
        w1t, b1, nullptr, nullptr, nullptr, nullptr, 0,
        t1, t1, t1, DMLP, DMODEL, 20);
    if (!bigws) {
        k_conv_slice<<<dim3(8, 64), 256, 0, stream>>>(w2 + (size_t)DMLP*DMODEL, w1t + (size_t)DMLP*DMODEL, DMLP, DMODEL);
    }
    // mlp2 phase B: split-K=2 partials + combine
    k_gemm_ms<3, 64, 128, float><<<dim3(8, 16, 2), 256, 0, stream>>>(
        t1, t1, t1,
        w2t, nullptr, nullptr, nullptr, nullptr, nullptr, 0,
        p0buf, p1buf, nullptr, DMODEL, DMLP, 20);
    k_mlp2fin<<<1024, 256, 0, stream>>>(p0buf, p1buf, b2, s1, mod,
                                        out_txt, out_img, out_tmp, 1280);
}